// Round 16
// baseline (831.339 us; speedup 1.0000x reference)
//
#include <hip/hip_runtime.h>

typedef unsigned short u16;
typedef __bf16 bfrag8 __attribute__((ext_vector_type(8)));
typedef float f32x4 __attribute__((ext_vector_type(4)));

#define MFMA16(a, b, c) __builtin_amdgcn_mfma_f32_16x16x32_bf16((a), (b), (c), 0, 0, 0)

static __device__ __forceinline__ u16 bf_bits(float f) {
  unsigned int u = __builtin_bit_cast(unsigned int, f);
  unsigned int r = (u + 0x7fffu + ((u >> 16) & 1u)) >> 16;
  return (u16)r;
}
static __device__ __forceinline__ float f_from_bits(u16 u) {
  unsigned int w = ((unsigned int)u) << 16;
  return __builtin_bit_cast(float, w);
}
static __device__ __forceinline__ void gload16(const void* g, void* l) {
  __builtin_amdgcn_global_load_lds(
      (const __attribute__((address_space(1))) void*)g,
      (__attribute__((address_space(3))) void*)l, 16, 0, 0);
}

// ---------------- transpose f32 [K][N] -> bf16 [N][K] ----------------
__global__ __launch_bounds__(256) void k_transpose_bf16(const float* __restrict__ src,
                                                        u16* __restrict__ dst,
                                                        int K, int N) {
  __shared__ float tile[32][33];
  const int n0 = blockIdx.x * 32;
  const int k0 = blockIdx.y * 32;
  const int t = threadIdx.x;
  const int lr = t >> 5;
  const int lc = t & 31;
#pragma unroll
  for (int i = 0; i < 4; ++i)
    tile[lr + i * 8][lc] = src[(size_t)(k0 + lr + i * 8) * N + n0 + lc];
  __syncthreads();
#pragma unroll
  for (int i = 0; i < 4; ++i)
    dst[(size_t)(n0 + lr + i * 8) * K + k0 + lc] = bf_bits(tile[lc][lr + i * 8]);
}

// ---------------- transpose V out of qkv: -> vtg[bh][128 d][2048 tok] ----------------
__global__ __launch_bounds__(256) void k_transpose_v(const u16* __restrict__ qkv,
                                                     u16* __restrict__ vtg) {
  __shared__ u16 tile[32][33];
  const int bh = blockIdx.z, b = bh >> 4, hh = bh & 15;
  const int s0 = blockIdx.x * 32, d0 = blockIdx.y * 32;
  const int t = threadIdx.x;
  const int lr = t >> 5, lc = t & 31;
#pragma unroll
  for (int i = 0; i < 4; ++i)
    tile[lr + i * 8][lc] =
        qkv[(size_t)(b * 2048 + s0 + lr + i * 8) * 6144 + 4096 + hh * 128 + d0 + lc];
  __syncthreads();
#pragma unroll
  for (int i = 0; i < 4; ++i)
    vtg[(size_t)bh * 128 * 2048 + (size_t)(d0 + lr + i * 8) * 2048 + s0 + lc] =
        tile[lc][lr + i * 8];
}

// ---------------- rmsnorm: f32 [rows][2048] -> bf16 ----------------
__global__ __launch_bounds__(256) void k_rmsnorm(const float* __restrict__ x,
                                                 const float* __restrict__ sc,
                                                 u16* __restrict__ o) {
  const int row = blockIdx.x;
  const int t = threadIdx.x;
  const float4* x4 = (const float4*)(x + (size_t)row * 2048);
  float4 a = x4[t];
  float4 b = x4[t + 256];
  float ss = a.x * a.x + a.y * a.y + a.z * a.z + a.w * a.w +
             b.x * b.x + b.y * b.y + b.z * b.z + b.w * b.w;
#pragma unroll
  for (int off = 32; off > 0; off >>= 1) ss += __shfl_down(ss, off);
  __shared__ float red[4];
  if ((t & 63) == 0) red[t >> 6] = ss;
  __syncthreads();
  const float inv = rsqrtf((red[0] + red[1] + red[2] + red[3]) * (1.0f / 2048.0f) + 1e-6f);
  const float4* s4 = (const float4*)sc;
  float4 sa = s4[t], sb = s4[t + 256];
  ushort4 pa, pb;
  pa.x = bf_bits(a.x * inv * sa.x); pa.y = bf_bits(a.y * inv * sa.y);
  pa.z = bf_bits(a.z * inv * sa.z); pa.w = bf_bits(a.w * inv * sa.w);
  pb.x = bf_bits(b.x * inv * sb.x); pb.y = bf_bits(b.y * inv * sb.y);
  pb.z = bf_bits(b.z * inv * sb.z); pb.w = bf_bits(b.w * inv * sb.w);
  *(ushort4*)(o + (size_t)row * 2048 + t * 4) = pa;
  *(ushort4*)(o + (size_t)row * 2048 + (t + 256) * 4) = pb;
}

// ---------------- combine: out = out + part0 + resid (all f32) ----------------
__global__ __launch_bounds__(256) void k_combine(float* __restrict__ out,
                                                 const float* __restrict__ part0,
                                                 const float* __restrict__ resid) {
  const size_t i = ((size_t)blockIdx.x * 256 + threadIdx.x) * 4;
  float4 o = *(const float4*)(out + i);
  float4 p = *(const float4*)(part0 + i);
  float4 r = *(const float4*)(resid + i);
  o.x += p.x + r.x; o.y += p.y + r.y; o.z += p.z + r.z; o.w += p.w + r.w;
  *(float4*)(out + i) = o;
}

// ======== 128x128 GEMM, 4 waves (64x64 wave tile), 4 blocks/CU (r12) ========
template <int EPI, int K, int PART>
__global__ __launch_bounds__(256, 4) void k_gemm(const u16* __restrict__ A,
                                                 const u16* __restrict__ Bt,
                                                 int M, int N,
                                                 float* __restrict__ outF,
                                                 u16* __restrict__ outB,
                                                 const float* __restrict__ resid,
                                                 const u16* __restrict__ gate) {
  __shared__ u16 sm[16384];  // 32 KiB: A | B
  char* smC = (char*)sm;
  const int nbx = gridDim.x;
  const int f = blockIdx.x + nbx * blockIdx.y;
  int m0, n0;
  if (PART == 0) {
    const int nsl = nbx >> 3;
    const int x = f & 7;
    const int j = f >> 3;
    n0 = (x * nsl + (j % nsl)) * 128;
    m0 = (j / nsl) * 128;
  } else {
    const int msl = (int)gridDim.y >> 3;
    const int x = f & 7;
    const int j = f >> 3;
    m0 = (x * msl + (j % msl)) * 128;
    n0 = (j / msl) * 128;
  }

  const int t = threadIdx.x;
  const int wid = t >> 6, lane = t & 63;
  const int wm = wid >> 1, wn = wid & 1;
  const int l15 = lane & 15, lhi = lane >> 4;
  const int lhi16 = lhi * 16;
  const int swz = (l15 & 7) << 4;

  f32x4 acc[4][4];
#pragma unroll
  for (int i = 0; i < 4; ++i)
#pragma unroll
    for (int j2 = 0; j2 < 4; ++j2) acc[i][j2] = (f32x4){0.f, 0.f, 0.f, 0.f};

  const int sr = lane >> 3;
  const int csw = (((lane & 7) * 16) ^ (sr << 4)) >> 1;
  const u16* Asrc = A + (size_t)(m0 + wid * 32 + sr) * K + csw;
  const u16* Bsrc = Bt + (size_t)(n0 + wid * 32 + sr) * K + csw;
  char* adst = smC + wid * 4096 + lane * 16;
  char* bdst = smC + 16384 + wid * 4096 + lane * 16;

  for (int kt = 0; kt < K / 64; ++kt) {
    __syncthreads();
    const u16* as = Asrc + kt * 64;
    const u16* bs = Bsrc + kt * 64;
#pragma unroll
    for (int c = 0; c < 4; ++c) {
      gload16(as + (size_t)c * 8 * K, adst + c * 1024);
      gload16(bs + (size_t)c * 8 * K, bdst + c * 1024);
    }
    asm volatile("s_waitcnt vmcnt(0)" ::: "memory");
    __syncthreads();

#pragma unroll
    for (int kh = 0; kh < 2; ++kh) {
      const int ko = kh * 64 + lhi16;
      bfrag8 a0 = *(const bfrag8*)(smC + (wm * 64 + 0 * 16 + l15) * 128 + (ko ^ swz));
      bfrag8 a1 = *(const bfrag8*)(smC + (wm * 64 + 1 * 16 + l15) * 128 + (ko ^ swz));
      bfrag8 a2 = *(const bfrag8*)(smC + (wm * 64 + 2 * 16 + l15) * 128 + (ko ^ swz));
      bfrag8 a3 = *(const bfrag8*)(smC + (wm * 64 + 3 * 16 + l15) * 128 + (ko ^ swz));
      bfrag8 b0 = *(const bfrag8*)(smC + 16384 + (wn * 64 + 0 * 16 + l15) * 128 + (ko ^ swz));
      bfrag8 b1 = *(const bfrag8*)(smC + 16384 + (wn * 64 + 1 * 16 + l15) * 128 + (ko ^ swz));
      bfrag8 b2 = *(const bfrag8*)(smC + 16384 + (wn * 64 + 2 * 16 + l15) * 128 + (ko ^ swz));
      bfrag8 b3 = *(const bfrag8*)(smC + 16384 + (wn * 64 + 3 * 16 + l15) * 128 + (ko ^ swz));
      acc[0][0] = MFMA16(a0, b0, acc[0][0]); acc[0][1] = MFMA16(a0, b1, acc[0][1]);
      acc[0][2] = MFMA16(a0, b2, acc[0][2]); acc[0][3] = MFMA16(a0, b3, acc[0][3]);
      acc[1][0] = MFMA16(a1, b0, acc[1][0]); acc[1][1] = MFMA16(a1, b1, acc[1][1]);
      acc[1][2] = MFMA16(a1, b2, acc[1][2]); acc[1][3] = MFMA16(a1, b3, acc[1][3]);
      acc[2][0] = MFMA16(a2, b0, acc[2][0]); acc[2][1] = MFMA16(a2, b1, acc[2][1]);
      acc[2][2] = MFMA16(a2, b2, acc[2][2]); acc[2][3] = MFMA16(a2, b3, acc[2][3]);
      acc[3][0] = MFMA16(a3, b0, acc[3][0]); acc[3][1] = MFMA16(a3, b1, acc[3][1]);
      acc[3][2] = MFMA16(a3, b2, acc[3][2]); acc[3][3] = MFMA16(a3, b3, acc[3][3]);
    }
  }

#pragma unroll
  for (int i = 0; i < 4; ++i) {
#pragma unroll
    for (int j2 = 0; j2 < 4; ++j2) {
      const int mr = m0 + wm * 64 + i * 16 + lhi * 4;
      const int nc = n0 + wn * 64 + j2 * 16 + l15;
#pragma unroll
      for (int r = 0; r < 4; ++r) {
        const size_t idx = (size_t)(mr + r) * N + nc;
        const float v = acc[i][j2][r];
        if (EPI == 0) {
          outB[idx] = bf_bits(v);
        } else if (EPI == 1) {
          outF[idx] = resid[idx] + v;
        } else {
          float g = f_from_bits(gate[idx]);
          float s = g / (1.f + __expf(-g));
          outB[idx] = bf_bits(v * s);
        }
      }
    }
  }
}

// ======== 128x256 dual-n GEMM: A staged once vs two B panels (r14/r15) ========
// EPI 0: bf16 out. EPI 1: f32 resid-add. EPI 2: raw f32 (split-K partial).
// KOFF: K-offset in u16 elements (split-K); KLEN: iterated K length.
// Requires grid >= 512 blocks for co-residency (r14 lesson).
template <int EPI, int K, int KLEN, int PART>
__global__ __launch_bounds__(256, 3) void k_gemm2(const u16* __restrict__ A,
                                                  const u16* __restrict__ Bt,
                                                  int N,
                                                  float* __restrict__ outF,
                                                  u16* __restrict__ outB,
                                                  const float* __restrict__ resid,
                                                  float* __restrict__ outF2) {
  __shared__ u16 sm[24576];  // 48 KiB: A | B0 | B1
  char* smC = (char*)sm;
  const int nbx = gridDim.x;  // n-pairs
  const int f = blockIdx.x + nbx * blockIdx.y;
  const int z = blockIdx.z;   // split-K half (0 if gridDim.z==1)
  int m0, np;
  if (PART == 0) {
    const int nsl = nbx >> 3;
    const int x = f & 7;
    const int j = f >> 3;
    np = x * nsl + (j % nsl);
    m0 = (j / nsl) * 128;
  } else {
    const int msl = (int)gridDim.y >> 3;
    const int x = f & 7;
    const int j = f >> 3;
    m0 = (x * msl + (j % msl)) * 128;
    np = j / msl;
  }
  const int n0 = np * 256;
  const int koff = z * KLEN;

  const int t = threadIdx.x;
  const int wid = t >> 6, lane = t & 63;
  const int wm = wid >> 1, wn = wid & 1;
  const int l15 = lane & 15, lhi = lane >> 4;
  const int lhi16 = lhi * 16;
  const int swz = (l15 & 7) << 4;

  f32x4 acc0[4][4], acc1[4][4];
#pragma unroll
  for (int i = 0; i < 4; ++i)
#pragma unroll
    for (int j2 = 0; j2 < 4; ++j2) {
      acc0[i][j2] = (f32x4){0.f, 0.f, 0.f, 0.f};
      acc1[i][j2] = (f32x4){0.f, 0.f, 0.f, 0.f};
    }

  const int sr = lane >> 3;
  const int csw = (((lane & 7) * 16) ^ (sr << 4)) >> 1;
  const u16* Asrc = A + (size_t)(m0 + wid * 32 + sr) * K + csw + koff;
  const u16* B0src = Bt + (size_t)(n0 + wid * 32 + sr) * K + csw + koff;
  const u16* B1src = Bt + (size_t)(n0 + 128 + wid * 32 + sr) * K + csw + koff;
  char* adst = smC + wid * 4096 + lane * 16;
  char* b0dst = smC + 16384 + wid * 4096 + lane * 16;
  char* b1dst = smC + 32768 + wid * 4096 + lane * 16;

  for (int kt = 0; kt < KLEN / 64; ++kt) {
    __syncthreads();
    const u16* as = Asrc + kt * 64;
    const u16* b0s = B0src + kt * 64;
    const u16* b1s = B1src + kt * 64;
#pragma unroll
    for (int c = 0; c < 4; ++c) {
      gload16(as + (size_t)c * 8 * K, adst + c * 1024);
      gload16(b0s + (size_t)c * 8 * K, b0dst + c * 1024);
      gload16(b1s + (size_t)c * 8 * K, b1dst + c * 1024);
    }
    asm volatile("s_waitcnt vmcnt(0)" ::: "memory");
    __syncthreads();

#pragma unroll
    for (int kh = 0; kh < 2; ++kh) {
      const int ko = (kh * 64 + lhi16);
      bfrag8 a0 = *(const bfrag8*)(smC + (wm * 64 + 0 * 16 + l15) * 128 + (ko ^ swz));
      bfrag8 a1 = *(const bfrag8*)(smC + (wm * 64 + 1 * 16 + l15) * 128 + (ko ^ swz));
      bfrag8 a2 = *(const bfrag8*)(smC + (wm * 64 + 2 * 16 + l15) * 128 + (ko ^ swz));
      bfrag8 a3 = *(const bfrag8*)(smC + (wm * 64 + 3 * 16 + l15) * 128 + (ko ^ swz));
      bfrag8 g0 = *(const bfrag8*)(smC + 16384 + (wn * 64 + 0 * 16 + l15) * 128 + (ko ^ swz));
      bfrag8 g1 = *(const bfrag8*)(smC + 16384 + (wn * 64 + 1 * 16 + l15) * 128 + (ko ^ swz));
      bfrag8 g2 = *(const bfrag8*)(smC + 16384 + (wn * 64 + 2 * 16 + l15) * 128 + (ko ^ swz));
      bfrag8 g3 = *(const bfrag8*)(smC + 16384 + (wn * 64 + 3 * 16 + l15) * 128 + (ko ^ swz));
      acc0[0][0] = MFMA16(a0, g0, acc0[0][0]); acc0[0][1] = MFMA16(a0, g1, acc0[0][1]);
      acc0[0][2] = MFMA16(a0, g2, acc0[0][2]); acc0[0][3] = MFMA16(a0, g3, acc0[0][3]);
      acc0[1][0] = MFMA16(a1, g0, acc0[1][0]); acc0[1][1] = MFMA16(a1, g1, acc0[1][1]);
      acc0[1][2] = MFMA16(a1, g2, acc0[1][2]); acc0[1][3] = MFMA16(a1, g3, acc0[1][3]);
      acc0[2][0] = MFMA16(a2, g0, acc0[2][0]); acc0[2][1] = MFMA16(a2, g1, acc0[2][1]);
      acc0[2][2] = MFMA16(a2, g2, acc0[2][2]); acc0[2][3] = MFMA16(a2, g3, acc0[2][3]);
      acc0[3][0] = MFMA16(a3, g0, acc0[3][0]); acc0[3][1] = MFMA16(a3, g1, acc0[3][1]);
      acc0[3][2] = MFMA16(a3, g2, acc0[3][2]); acc0[3][3] = MFMA16(a3, g3, acc0[3][3]);
      bfrag8 u0 = *(const bfrag8*)(smC + 32768 + (wn * 64 + 0 * 16 + l15) * 128 + (ko ^ swz));
      bfrag8 u1 = *(const bfrag8*)(smC + 32768 + (wn * 64 + 1 * 16 + l15) * 128 + (ko ^ swz));
      bfrag8 u2 = *(const bfrag8*)(smC + 32768 + (wn * 64 + 2 * 16 + l15) * 128 + (ko ^ swz));
      bfrag8 u3 = *(const bfrag8*)(smC + 32768 + (wn * 64 + 3 * 16 + l15) * 128 + (ko ^ swz));
      acc1[0][0] = MFMA16(a0, u0, acc1[0][0]); acc1[0][1] = MFMA16(a0, u1, acc1[0][1]);
      acc1[0][2] = MFMA16(a0, u2, acc1[0][2]); acc1[0][3] = MFMA16(a0, u3, acc1[0][3]);
      acc1[1][0] = MFMA16(a1, u0, acc1[1][0]); acc1[1][1] = MFMA16(a1, u1, acc1[1][1]);
      acc1[1][2] = MFMA16(a1, u2, acc1[1][2]); acc1[1][3] = MFMA16(a1, u3, acc1[1][3]);
      acc1[2][0] = MFMA16(a2, u0, acc1[2][0]); acc1[2][1] = MFMA16(a2, u1, acc1[2][1]);
      acc1[2][2] = MFMA16(a2, u2, acc1[2][2]); acc1[2][3] = MFMA16(a2, u3, acc1[2][3]);
      acc1[3][0] = MFMA16(a3, u0, acc1[3][0]); acc1[3][1] = MFMA16(a3, u1, acc1[3][1]);
      acc1[3][2] = MFMA16(a3, u2, acc1[3][2]); acc1[3][3] = MFMA16(a3, u3, acc1[3][3]);
    }
  }

  float* wout = (EPI == 2 && blockIdx.z == 1) ? outF2 : outF;
#pragma unroll
  for (int h = 0; h < 2; ++h) {
#pragma unroll
    for (int i = 0; i < 4; ++i) {
#pragma unroll
      for (int j2 = 0; j2 < 4; ++j2) {
        const int mr = m0 + wm * 64 + i * 16 + lhi * 4;
        const int nc = n0 + h * 128 + wn * 64 + j2 * 16 + l15;
#pragma unroll
        for (int r = 0; r < 4; ++r) {
          const size_t idx = (size_t)(mr + r) * N + nc;
          const float v = h ? acc1[i][j2][r] : acc0[i][j2][r];
          if (EPI == 0) {
            outB[idx] = bf_bits(v);
          } else if (EPI == 1) {
            outF[idx] = resid[idx] + v;
          } else {
            wout[idx] = v;
          }
        }
      }
    }
  }
}

// ======== fused MLP GEMM: h = up(x) * silu(gate(x)), 128x128 tile (r10/r13) ========
template <int K>
__global__ __launch_bounds__(256, 3) void k_gemm_mlp(const u16* __restrict__ A,
                                                     const u16* __restrict__ Bg,
                                                     const u16* __restrict__ Bu,
                                                     int N,
                                                     u16* __restrict__ outB) {
  __shared__ u16 sm[24576];  // 48 KiB: A | Bg | Bu
  char* smC = (char*)sm;
  const int nbx = gridDim.x;
  const int f = blockIdx.x + nbx * blockIdx.y;
  const int nsl = nbx >> 3;
  const int x = f & 7;
  const int j = f >> 3;
  const int n0 = (x * nsl + (j % nsl)) * 128;
  const int m0 = (j / nsl) * 128;

  const int t = threadIdx.x;
  const int wid = t >> 6, lane = t & 63;
  const int wm = wid >> 1, wn = wid & 1;
  const int l15 = lane & 15, lhi = lane >> 4;
  const int lhi16 = lhi * 16;
  const int swz = (l15 & 7) << 4;

  f32x4 accg[4][4], accu[4][4];
#pragma unroll
  for (int i = 0; i < 4; ++i)
#pragma unroll
    for (int j2 = 0; j2 < 4; ++j2) {
      accg[i][j2] = (f32x4){0.f, 0.f, 0.f, 0.f};
      accu[i][j2] = (f32x4){0.f, 0.f, 0.f, 0.f};
    }

  const int sr = lane >> 3;
  const int csw = (((lane & 7) * 16) ^ (sr << 4)) >> 1;
  const u16* Asrc = A + (size_t)(m0 + wid * 32 + sr) * K + csw;
  const u16* Bgsrc = Bg + (size_t)(n0 + wid * 32 + sr) * K + csw;
  const u16* Busrc = Bu + (size_t)(n0 + wid * 32 + sr) * K + csw;
  char* adst = smC + wid * 4096 + lane * 16;
  char* bgdst = smC + 16384 + wid * 4096 + lane * 16;
  char* budst = smC + 32768 + wid * 4096 + lane * 16;

  for (int kt = 0; kt < K / 64; ++kt) {
    __syncthreads();
    const u16* as = Asrc + kt * 64;
    const u16* gs = Bgsrc + kt * 64;
    const u16* us = Busrc + kt * 64;
#pragma unroll
    for (int c = 0; c < 4; ++c) {
      gload16(as + (size_t)c * 8 * K, adst + c * 1024);
      gload16(gs + (size_t)c * 8 * K, bgdst + c * 1024);
      gload16(us + (size_t)c * 8 * K, budst + c * 1024);
    }
    asm volatile("s_waitcnt vmcnt(0)" ::: "memory");
    __syncthreads();

#pragma unroll
    for (int kh = 0; kh < 2; ++kh) {
      const int ko = (kh * 64 + lhi16);
      bfrag8 a0 = *(const bfrag8*)(smC + (wm * 64 + 0 * 16 + l15) * 128 + (ko ^ swz));
      bfrag8 a1 = *(const bfrag8*)(smC + (wm * 64 + 1 * 16 + l15) * 128 + (ko ^ swz));
      bfrag8 a2 = *(const bfrag8*)(smC + (wm * 64 + 2 * 16 + l15) * 128 + (ko ^ swz));
      bfrag8 a3 = *(const bfrag8*)(smC + (wm * 64 + 3 * 16 + l15) * 128 + (ko ^ swz));
      bfrag8 g0 = *(const bfrag8*)(smC + 16384 + (wn * 64 + 0 * 16 + l15) * 128 + (ko ^ swz));
      bfrag8 g1 = *(const bfrag8*)(smC + 16384 + (wn * 64 + 1 * 16 + l15) * 128 + (ko ^ swz));
      bfrag8 g2 = *(const bfrag8*)(smC + 16384 + (wn * 64 + 2 * 16 + l15) * 128 + (ko ^ swz));
      bfrag8 g3 = *(const bfrag8*)(smC + 16384 + (wn * 64 + 3 * 16 + l15) * 128 + (ko ^ swz));
      accg[0][0] = MFMA16(a0, g0, accg[0][0]); accg[0][1] = MFMA16(a0, g1, accg[0][1]);
      accg[0][2] = MFMA16(a0, g2, accg[0][2]); accg[0][3] = MFMA16(a0, g3, accg[0][3]);
      accg[1][0] = MFMA16(a1, g0, accg[1][0]); accg[1][1] = MFMA16(a1, g1, accg[1][1]);
      accg[1][2] = MFMA16(a1, g2, accg[1][2]); accg[1][3] = MFMA16(a1, g3, accg[1][3]);
      accg[2][0] = MFMA16(a2, g0, accg[2][0]); accg[2][1] = MFMA16(a2, g1, accg[2][1]);
      accg[2][2] = MFMA16(a2, g2, accg[2][2]); accg[2][3] = MFMA16(a2, g3, accg[2][3]);
      accg[3][0] = MFMA16(a3, g0, accg[3][0]); accg[3][1] = MFMA16(a3, g1, accg[3][1]);
      accg[3][2] = MFMA16(a3, g2, accg[3][2]); accg[3][3] = MFMA16(a3, g3, accg[3][3]);
      bfrag8 u0 = *(const bfrag8*)(smC + 32768 + (wn * 64 + 0 * 16 + l15) * 128 + (ko ^ swz));
      bfrag8 u1 = *(const bfrag8*)(smC + 32768 + (wn * 64 + 1 * 16 + l15) * 128 + (ko ^ swz));
      bfrag8 u2 = *(const bfrag8*)(smC + 32768 + (wn * 64 + 2 * 16 + l15) * 128 + (ko ^ swz));
      bfrag8 u3 = *(const bfrag8*)(smC + 32768 + (wn * 64 + 3 * 16 + l15) * 128 + (ko ^ swz));
      accu[0][0] = MFMA16(a0, u0, accu[0][0]); accu[0][1] = MFMA16(a0, u1, accu[0][1]);
      accu[0][2] = MFMA16(a0, u2, accu[0][2]); accu[0][3] = MFMA16(a0, u3, accu[0][3]);
      accu[1][0] = MFMA16(a1, u0, accu[1][0]); accu[1][1] = MFMA16(a1, u1, accu[1][1]);
      accu[1][2] = MFMA16(a1, u2, accu[1][2]); accu[1][3] = MFMA16(a1, u3, accu[1][3]);
      accu[2][0] = MFMA16(a2, u0, accu[2][0]); accu[2][1] = MFMA16(a2, u1, accu[2][1]);
      accu[2][2] = MFMA16(a2, u2, accu[2][2]); accu[2][3] = MFMA16(a2, u3, accu[2][3]);
      accu[3][0] = MFMA16(a3, u0, accu[3][0]); accu[3][1] = MFMA16(a3, u1, accu[3][1]);
      accu[3][2] = MFMA16(a3, u2, accu[3][2]); accu[3][3] = MFMA16(a3, u3, accu[3][3]);
    }
  }

#pragma unroll
  for (int i = 0; i < 4; ++i) {
#pragma unroll
    for (int j2 = 0; j2 < 4; ++j2) {
      const int mr = m0 + wm * 64 + i * 16 + lhi * 4;
      const int nc = n0 + wn * 64 + j2 * 16 + l15;
#pragma unroll
      for (int r = 0; r < 4; ++r) {
        const float g = accg[i][j2][r];
        const float u = accu[i][j2][r];
        const float s = g / (1.f + __expf(-g));
        outB[(size_t)(mr + r) * N + nc] = bf_bits(u * s);
      }
    }
  }
}

// ---------------- causal flash attention (8 waves, QBLK=128, KVBLK=64) ----------------
__global__ __launch_bounds__(512) void k_attn(const u16* __restrict__ qkv,
                                              const u16* __restrict__ vtg,
                                              u16* __restrict__ out) {
  const int S = 2048, LD = 6144;
  const float scale = 0.0883883476483184405f;  // 1/sqrt(128)
  const int fid = blockIdx.x;       // 0..511
  const int p = fid >> 1, s = fid & 1;
  const int bh = p & 31;
  const int pq = p >> 5;            // 0..7
  const int qt = s ? (15 - pq) : pq;
  const int b = bh >> 4, hh = bh & 15;
  const int t = threadIdx.x;
  const int wave = t >> 6, lane = t & 63;
  const int l15 = lane & 15, lhi = lane >> 4;
  const int lhi16 = lhi * 16;
  const int swz = (l15 & 7) << 4;

  __shared__ u16 Kt[64 * 128];
  __shared__ u16 Vt[128 * 64];
  __shared__ u16 Pl[8][16][72];
  char* KtC = (char*)Kt;
  char* VtC = (char*)Vt;

  const int qrow = qt * 128 + wave * 16 + l15;
  const size_t qoff = (size_t)(b * S + qrow) * LD + hh * 128 + lhi * 8;
  bfrag8 qf[4];
#pragma unroll
  for (int ks = 0; ks < 4; ++ks) qf[ks] = *(const bfrag8*)(qkv + qoff + ks * 32);

  f32x4 oacc[8];
#pragma unroll
  for (int j = 0; j < 8; ++j) oacc[j] = (f32x4){0.f, 0.f, 0.f, 0.f};
  float m_i[4], l_i[4];
#pragma unroll
  for (int r = 0; r < 4; ++r) { m_i[r] = -INFINITY; l_i[r] = 0.f; }

  const int q_my = qt * 128 + wave * 16 + lhi * 4;
  const int q_wave_last = qt * 128 + wave * 16 + 15;

  const int keyA = t >> 4, keyB = 32 + (t >> 4);
  const int oK = (t & 15) * 16;
  const int dA = t >> 3, dB = 64 + (t >> 3);
  const int oV = (t & 7) * 16;
  const u16* kbase = qkv + (size_t)(b * S) * LD + 2048 + hh * 128;
  const u16* vbase = vtg + (size_t)bh * 128 * S;
  const u16* ksrcA = kbase + (size_t)keyA * LD + ((oK ^ ((keyA & 7) << 4)) >> 1);
  const u16* ksrcB = kbase + (size_t)keyB * LD + ((oK ^ ((keyB & 7) << 4)) >> 1);
  const u16* vsrcA = vbase + (size_t)dA * S + ((oV ^ ((dA & 7) << 4)) >> 1);
  const u16* vsrcB = vbase + (size_t)dB * S + ((oV ^ ((dB & 7) << 4)) >> 1);
  const unsigned int ldso0 = wave * 1024 + lane * 16;
  const unsigned int ldso1 = 8192 + wave * 1024 + lane * 16;
  const size_t kstep = (size_t)64 * LD;

  const int kt_max = 2 * qt + 1;
  for (int kt = 0; kt <= kt_max; ++kt) {
    __syncthreads();
    gload16(ksrcA + (size_t)kt * kstep, KtC + ldso0);
    gload16(ksrcB + (size_t)kt * kstep, KtC + ldso1);
    gload16(vsrcA + kt * 64, VtC + ldso0);
    gload16(vsrcB + kt * 64, VtC + ldso1);
    __syncthreads();

    if (kt * 64 <= q_wave_last) {
      f32x4 sfr[4];
#pragma unroll
      for (int j = 0; j < 4; ++j) {
        sfr[j] = (f32x4){0.f, 0.f, 0.f, 0.f};
        const int krow = j * 16 + l15;
#pragma unroll
        for (int ks = 0; ks < 4; ++ks) {
          bfrag8 kf = *(const bfrag8*)(KtC + krow * 256 + ((ks * 64 + lhi16) ^ swz));
          sfr[j] = MFMA16(qf[ks], kf, sfr[j]);
        }
      }
      float sv[4][4], rmax[4];
#pragma unroll
      for (int r = 0; r < 4; ++r) rmax[r] = -INFINITY;
#pragma unroll
      for (int j = 0; j < 4; ++j) {
        const int key = kt * 64 + j * 16 + l15;
#pragma unroll
        for (int r = 0; r < 4; ++r) {
          float v = sfr[j][r] * scale;
          v = (key <= q_my + r) ? v : -INFINITY;
          sv[j][r] = v;
          rmax[r] = fmaxf(rmax[r], v);
        }
      }
#pragma unroll
      for (int r = 0; r < 4; ++r) {
        float v = rmax[r];
        v = fmaxf(v, __shfl_xor(v, 1));
        v = fmaxf(v, __shfl_xor(v, 2));
        v = fmaxf(v, __shfl_xor(v, 4));
        v = fmaxf(v, __shfl_xor(v, 8));
        rmax[r] = v;
      }
      float alpha[4], rsum[4];
#pragma unroll
      for (int r = 0; r < 4; ++r) {
        float mn = fmaxf(m_i[r], rmax[r]);
        alpha[r] = __expf(m_i[r] - mn);
        m_i[r] = mn;
        rsum[r] = 0.f;
      }
#pragma unroll
      for (int j = 0; j < 4; ++j) {
#pragma unroll
        for (int r = 0; r < 4; ++r) {
          float p2 = __expf(sv[j][r] - m_i[r]);
          rsum[r] += p2;
          Pl[wave][lhi * 4 + r][j * 16 + l15] = bf_bits(p2);
        }
      }
#pragma unroll
      for (int r = 0; r < 4; ++r) {
        float v = rsum[r];
        v += __shfl_xor(v, 1); v += __shfl_xor(v, 2);
        v += __shfl_xor(v, 4); v += __shfl_xor(v, 8);
        l_i[r] = l_i[r] * alpha[r] + v;
      }
#pragma unroll
      for (int j = 0; j < 8; ++j)
#pragma unroll
        for (int r = 0; r < 4; ++r) oacc[j][r] *= alpha[r];

#pragma unroll
      for (int ks2 = 0; ks2 < 2; ++ks2) {
        bfrag8 pf = *(const bfrag8*)&Pl[wave][l15][ks2 * 32 + lhi * 8];
#pragma unroll
        for (int j = 0; j < 8; ++j) {
          const int d = j * 16 + l15;
          bfrag8 vf = *(const bfrag8*)(VtC + d * 128 + ((ks2 * 64 + lhi16) ^ swz));
          oacc[j] = MFMA16(pf, vf, oacc[j]);
        }
      }
    }
  }

#pragma unroll
  for (int r = 0; r < 4; ++r) {
    const float inv = 1.f / l_i[r];
    const size_t tok = (size_t)b * S + qt * 128 + wave * 16 + lhi * 4 + r;
#pragma unroll
    for (int j = 0; j < 8; ++j)
      out[tok * 2048 + hh * 128 + j * 16 + l15] = bf_bits(oacc[j][r] * inv);
  }
}

// ---------------- launch ----------------
extern "C" void kernel_launch(void* const* d_in, const int* in_sizes, int n_in,
                              void* d_out, int out_size, void* d_ws, size_t ws_size,
                              hipStream_t stream) {
  (void)in_sizes; (void)n_in; (void)out_size; (void)ws_size;
  const float* x      = (const float*)d_in[0];
  const float* w_qkv  = (const float*)d_in[1];
  const float* w_o    = (const float*)d_in[2];
  const float* w_up   = (const float*)d_in[3];
  const float* w_gate = (const float*)d_in[4];
  const float* w_down = (const float*)d_in[5];
  const float* scale1 = (const float*)d_in[6];
  const float* scale2 = (const float*)d_in[7];
  float* out = (float*)d_out;

  u16* B       = (u16*)d_ws;
  u16* wqkvT   = B;                               // [6144][2048]
  u16* woT     = wqkvT  + (size_t)6144 * 2048;    // [2048][2048]
  u16* wgateT  = woT    + (size_t)2048 * 2048;    // [8192][2048]
  u16* wupT    = wgateT + (size_t)8192 * 2048;    // [8192][2048]
  u16* wdownT  = wupT   + (size_t)8192 * 2048;    // [2048][8192]
  u16* xn      = wdownT + (size_t)2048 * 8192;    // [4096][2048]
  u16* qkvb    = xn     + (size_t)4096 * 2048;    // [4096][6144]
  u16* attnb   = qkvb   + (size_t)4096 * 6144;    // [4096][2048]
  float* y1    = (float*)(attnb + (size_t)4096 * 2048);  // [4096][2048] f32
  u16* vtg     = (u16*)y1;     // alias: vtg dead before y1 written
  u16* hbuf    = qkvb;         // alias: qkv+attn dead after out-proj
  float* part0 = (float*)wqkvT;  // alias: wqkvT+woT (32MB) dead after out-proj

  dim3 blk(256);
  k_transpose_bf16<<<dim3(192, 64), blk, 0, stream>>>(w_qkv,  wqkvT,  2048, 6144);
  k_transpose_bf16<<<dim3(64, 64),  blk, 0, stream>>>(w_o,    woT,    2048, 2048);
  k_transpose_bf16<<<dim3(256, 64), blk, 0, stream>>>(w_gate, wgateT, 2048, 8192);
  k_transpose_bf16<<<dim3(256, 64), blk, 0, stream>>>(w_up,   wupT,   2048, 8192);
  k_transpose_bf16<<<dim3(64, 256), blk, 0, stream>>>(w_down, wdownT, 8192, 2048);

  k_rmsnorm<<<4096, blk, 0, stream>>>(x, scale1, xn);
  k_gemm2<0, 2048, 2048, 0><<<dim3(24, 32), blk, 0, stream>>>(xn, wqkvT, 6144, nullptr, qkvb, nullptr, nullptr);
  k_transpose_v<<<dim3(64, 4, 32), blk, 0, stream>>>(qkvb, vtg);
  k_attn<<<dim3(512), dim3(512), 0, stream>>>(qkvb, vtg, attnb);
  k_gemm<1, 2048, 1><<<dim3(16, 32), blk, 0, stream>>>(attnb, woT, 4096, 2048, y1, nullptr, x, nullptr);
  k_rmsnorm<<<4096, blk, 0, stream>>>(y1, scale2, xn);
  k_gemm_mlp<2048><<<dim3(64, 32), blk, 0, stream>>>(xn, wgateT, wupT, 8192, hbuf);
  // down, split-K x2 (dual-n, 2 blocks/CU): z=0 -> part0, z=1 -> out; then combine.
  k_gemm2<2, 8192, 4096, 1><<<dim3(8, 32, 2), blk, 0, stream>>>(hbuf, wdownT, 2048, part0, nullptr, nullptr, out);
  k_combine<<<8192, blk, 0, stream>>>(out, part0, y1);
}

// Round 17
// 818.981 us; speedup vs baseline: 1.0151x; 1.0151x over previous
//
#include <hip/hip_runtime.h>

typedef unsigned short u16;
typedef __bf16 bfrag8 __attribute__((ext_vector_type(8)));
typedef float f32x4 __attribute__((ext_vector_type(4)));

#define MFMA16(a, b, c) __builtin_amdgcn_mfma_f32_16x16x32_bf16((a), (b), (c), 0, 0, 0)

static __device__ __forceinline__ u16 bf_bits(float f) {
  unsigned int u = __builtin_bit_cast(unsigned int, f);
  unsigned int r = (u + 0x7fffu + ((u >> 16) & 1u)) >> 16;
  return (u16)r;
}
static __device__ __forceinline__ float f_from_bits(u16 u) {
  unsigned int w = ((unsigned int)u) << 16;
  return __builtin_bit_cast(float, w);
}
static __device__ __forceinline__ void gload16(const void* g, void* l) {
  __builtin_amdgcn_global_load_lds(
      (const __attribute__((address_space(1))) void*)g,
      (__attribute__((address_space(3))) void*)l, 16, 0, 0);
}

// ---------------- transpose f32 [K][N] -> bf16 [N][K] ----------------
__global__ __launch_bounds__(256) void k_transpose_bf16(const float* __restrict__ src,
                                                        u16* __restrict__ dst,
                                                        int K, int N) {
  __shared__ float tile[32][33];
  const int n0 = blockIdx.x * 32;
  const int k0 = blockIdx.y * 32;
  const int t = threadIdx.x;
  const int lr = t >> 5;
  const int lc = t & 31;
#pragma unroll
  for (int i = 0; i < 4; ++i)
    tile[lr + i * 8][lc] = src[(size_t)(k0 + lr + i * 8) * N + n0 + lc];
  __syncthreads();
#pragma unroll
  for (int i = 0; i < 4; ++i)
    dst[(size_t)(n0 + lr + i * 8) * K + k0 + lc] = bf_bits(tile[lc][lr + i * 8]);
}

// ---------------- transpose V out of qkv: -> vtg[bh][128 d][2048 tok] ----------------
__global__ __launch_bounds__(256) void k_transpose_v(const u16* __restrict__ qkv,
                                                     u16* __restrict__ vtg) {
  __shared__ u16 tile[32][33];
  const int bh = blockIdx.z, b = bh >> 4, hh = bh & 15;
  const int s0 = blockIdx.x * 32, d0 = blockIdx.y * 32;
  const int t = threadIdx.x;
  const int lr = t >> 5, lc = t & 31;
#pragma unroll
  for (int i = 0; i < 4; ++i)
    tile[lr + i * 8][lc] =
        qkv[(size_t)(b * 2048 + s0 + lr + i * 8) * 6144 + 4096 + hh * 128 + d0 + lc];
  __syncthreads();
#pragma unroll
  for (int i = 0; i < 4; ++i)
    vtg[(size_t)bh * 128 * 2048 + (size_t)(d0 + lr + i * 8) * 2048 + s0 + lc] =
        tile[lc][lr + i * 8];
}

// ---------------- rmsnorm: f32 [rows][2048] -> bf16 ----------------
__global__ __launch_bounds__(256) void k_rmsnorm(const float* __restrict__ x,
                                                 const float* __restrict__ sc,
                                                 u16* __restrict__ o) {
  const int row = blockIdx.x;
  const int t = threadIdx.x;
  const float4* x4 = (const float4*)(x + (size_t)row * 2048);
  float4 a = x4[t];
  float4 b = x4[t + 256];
  float ss = a.x * a.x + a.y * a.y + a.z * a.z + a.w * a.w +
             b.x * b.x + b.y * b.y + b.z * b.z + b.w * b.w;
#pragma unroll
  for (int off = 32; off > 0; off >>= 1) ss += __shfl_down(ss, off);
  __shared__ float red[4];
  if ((t & 63) == 0) red[t >> 6] = ss;
  __syncthreads();
  const float inv = rsqrtf((red[0] + red[1] + red[2] + red[3]) * (1.0f / 2048.0f) + 1e-6f);
  const float4* s4 = (const float4*)sc;
  float4 sa = s4[t], sb = s4[t + 256];
  ushort4 pa, pb;
  pa.x = bf_bits(a.x * inv * sa.x); pa.y = bf_bits(a.y * inv * sa.y);
  pa.z = bf_bits(a.z * inv * sa.z); pa.w = bf_bits(a.w * inv * sa.w);
  pb.x = bf_bits(b.x * inv * sb.x); pb.y = bf_bits(b.y * inv * sb.y);
  pb.z = bf_bits(b.z * inv * sb.z); pb.w = bf_bits(b.w * inv * sb.w);
  *(ushort4*)(o + (size_t)row * 2048 + t * 4) = pa;
  *(ushort4*)(o + (size_t)row * 2048 + (t + 256) * 4) = pb;
}

// ======== 128x128 GEMM, 4 waves (64x64 wave tile), 4 blocks/CU (r12) ========
// PART=0: XCD owns n-slice. PART=1: XCD owns m-slice (out/down).
template <int EPI, int K, int PART>
__global__ __launch_bounds__(256, 4) void k_gemm(const u16* __restrict__ A,
                                                 const u16* __restrict__ Bt,
                                                 int M, int N,
                                                 float* __restrict__ outF,
                                                 u16* __restrict__ outB,
                                                 const float* __restrict__ resid,
                                                 const u16* __restrict__ gate) {
  __shared__ u16 sm[16384];  // 32 KiB: A | B
  char* smC = (char*)sm;
  const int nbx = gridDim.x;
  const int f = blockIdx.x + nbx * blockIdx.y;
  int m0, n0;
  if (PART == 0) {
    const int nsl = nbx >> 3;
    const int x = f & 7;
    const int j = f >> 3;
    n0 = (x * nsl + (j % nsl)) * 128;
    m0 = (j / nsl) * 128;
  } else {
    const int msl = (int)gridDim.y >> 3;
    const int x = f & 7;
    const int j = f >> 3;
    m0 = (x * msl + (j % msl)) * 128;
    n0 = (j / msl) * 128;
  }

  const int t = threadIdx.x;
  const int wid = t >> 6, lane = t & 63;
  const int wm = wid >> 1, wn = wid & 1;
  const int l15 = lane & 15, lhi = lane >> 4;
  const int lhi16 = lhi * 16;
  const int swz = (l15 & 7) << 4;

  f32x4 acc[4][4];
#pragma unroll
  for (int i = 0; i < 4; ++i)
#pragma unroll
    for (int j2 = 0; j2 < 4; ++j2) acc[i][j2] = (f32x4){0.f, 0.f, 0.f, 0.f};

  const int sr = lane >> 3;
  const int csw = (((lane & 7) * 16) ^ (sr << 4)) >> 1;
  const u16* Asrc = A + (size_t)(m0 + wid * 32 + sr) * K + csw;
  const u16* Bsrc = Bt + (size_t)(n0 + wid * 32 + sr) * K + csw;
  char* adst = smC + wid * 4096 + lane * 16;
  char* bdst = smC + 16384 + wid * 4096 + lane * 16;

  for (int kt = 0; kt < K / 64; ++kt) {
    __syncthreads();
    const u16* as = Asrc + kt * 64;
    const u16* bs = Bsrc + kt * 64;
#pragma unroll
    for (int c = 0; c < 4; ++c) {
      gload16(as + (size_t)c * 8 * K, adst + c * 1024);
      gload16(bs + (size_t)c * 8 * K, bdst + c * 1024);
    }
    asm volatile("s_waitcnt vmcnt(0)" ::: "memory");
    __syncthreads();

#pragma unroll
    for (int kh = 0; kh < 2; ++kh) {
      const int ko = kh * 64 + lhi16;
      bfrag8 a0 = *(const bfrag8*)(smC + (wm * 64 + 0 * 16 + l15) * 128 + (ko ^ swz));
      bfrag8 a1 = *(const bfrag8*)(smC + (wm * 64 + 1 * 16 + l15) * 128 + (ko ^ swz));
      bfrag8 a2 = *(const bfrag8*)(smC + (wm * 64 + 2 * 16 + l15) * 128 + (ko ^ swz));
      bfrag8 a3 = *(const bfrag8*)(smC + (wm * 64 + 3 * 16 + l15) * 128 + (ko ^ swz));
      bfrag8 b0 = *(const bfrag8*)(smC + 16384 + (wn * 64 + 0 * 16 + l15) * 128 + (ko ^ swz));
      bfrag8 b1 = *(const bfrag8*)(smC + 16384 + (wn * 64 + 1 * 16 + l15) * 128 + (ko ^ swz));
      bfrag8 b2 = *(const bfrag8*)(smC + 16384 + (wn * 64 + 2 * 16 + l15) * 128 + (ko ^ swz));
      bfrag8 b3 = *(const bfrag8*)(smC + 16384 + (wn * 64 + 3 * 16 + l15) * 128 + (ko ^ swz));
      acc[0][0] = MFMA16(a0, b0, acc[0][0]); acc[0][1] = MFMA16(a0, b1, acc[0][1]);
      acc[0][2] = MFMA16(a0, b2, acc[0][2]); acc[0][3] = MFMA16(a0, b3, acc[0][3]);
      acc[1][0] = MFMA16(a1, b0, acc[1][0]); acc[1][1] = MFMA16(a1, b1, acc[1][1]);
      acc[1][2] = MFMA16(a1, b2, acc[1][2]); acc[1][3] = MFMA16(a1, b3, acc[1][3]);
      acc[2][0] = MFMA16(a2, b0, acc[2][0]); acc[2][1] = MFMA16(a2, b1, acc[2][1]);
      acc[2][2] = MFMA16(a2, b2, acc[2][2]); acc[2][3] = MFMA16(a2, b3, acc[2][3]);
      acc[3][0] = MFMA16(a3, b0, acc[3][0]); acc[3][1] = MFMA16(a3, b1, acc[3][1]);
      acc[3][2] = MFMA16(a3, b2, acc[3][2]); acc[3][3] = MFMA16(a3, b3, acc[3][3]);
    }
  }

#pragma unroll
  for (int i = 0; i < 4; ++i) {
#pragma unroll
    for (int j2 = 0; j2 < 4; ++j2) {
      const int mr = m0 + wm * 64 + i * 16 + lhi * 4;
      const int nc = n0 + wn * 64 + j2 * 16 + l15;
#pragma unroll
      for (int r = 0; r < 4; ++r) {
        const size_t idx = (size_t)(mr + r) * N + nc;
        const float v = acc[i][j2][r];
        if (EPI == 0) {
          outB[idx] = bf_bits(v);
        } else if (EPI == 1) {
          outF[idx] = resid[idx] + v;
        } else {
          float g = f_from_bits(gate[idx]);
          float s = g / (1.f + __expf(-g));
          outB[idx] = bf_bits(v * s);
        }
      }
    }
  }
}

// ======== 128x256 dual-n GEMM (qkv only: 768 blocks = 3/CU exact) ========
template <int EPI, int K, int PART>
__global__ __launch_bounds__(256, 3) void k_gemm2(const u16* __restrict__ A,
                                                  const u16* __restrict__ Bt,
                                                  int N,
                                                  float* __restrict__ outF,
                                                  u16* __restrict__ outB,
                                                  const float* __restrict__ resid) {
  __shared__ u16 sm[24576];  // 48 KiB: A | B0 | B1
  char* smC = (char*)sm;
  const int nbx = gridDim.x;  // n-pairs
  const int f = blockIdx.x + nbx * blockIdx.y;
  int m0, np;
  if (PART == 0) {
    const int nsl = nbx >> 3;
    const int x = f & 7;
    const int j = f >> 3;
    np = x * nsl + (j % nsl);
    m0 = (j / nsl) * 128;
  } else {
    const int msl = (int)gridDim.y >> 3;
    const int x = f & 7;
    const int j = f >> 3;
    m0 = (x * msl + (j % msl)) * 128;
    np = j / msl;
  }
  const int n0 = np * 256;

  const int t = threadIdx.x;
  const int wid = t >> 6, lane = t & 63;
  const int wm = wid >> 1, wn = wid & 1;
  const int l15 = lane & 15, lhi = lane >> 4;
  const int lhi16 = lhi * 16;
  const int swz = (l15 & 7) << 4;

  f32x4 acc0[4][4], acc1[4][4];
#pragma unroll
  for (int i = 0; i < 4; ++i)
#pragma unroll
    for (int j2 = 0; j2 < 4; ++j2) {
      acc0[i][j2] = (f32x4){0.f, 0.f, 0.f, 0.f};
      acc1[i][j2] = (f32x4){0.f, 0.f, 0.f, 0.f};
    }

  const int sr = lane >> 3;
  const int csw = (((lane & 7) * 16) ^ (sr << 4)) >> 1;
  const u16* Asrc = A + (size_t)(m0 + wid * 32 + sr) * K + csw;
  const u16* B0src = Bt + (size_t)(n0 + wid * 32 + sr) * K + csw;
  const u16* B1src = Bt + (size_t)(n0 + 128 + wid * 32 + sr) * K + csw;
  char* adst = smC + wid * 4096 + lane * 16;
  char* b0dst = smC + 16384 + wid * 4096 + lane * 16;
  char* b1dst = smC + 32768 + wid * 4096 + lane * 16;

  for (int kt = 0; kt < K / 64; ++kt) {
    __syncthreads();
    const u16* as = Asrc + kt * 64;
    const u16* b0s = B0src + kt * 64;
    const u16* b1s = B1src + kt * 64;
#pragma unroll
    for (int c = 0; c < 4; ++c) {
      gload16(as + (size_t)c * 8 * K, adst + c * 1024);
      gload16(b0s + (size_t)c * 8 * K, b0dst + c * 1024);
      gload16(b1s + (size_t)c * 8 * K, b1dst + c * 1024);
    }
    asm volatile("s_waitcnt vmcnt(0)" ::: "memory");
    __syncthreads();

#pragma unroll
    for (int kh = 0; kh < 2; ++kh) {
      const int ko = (kh * 64 + lhi16);
      bfrag8 a0 = *(const bfrag8*)(smC + (wm * 64 + 0 * 16 + l15) * 128 + (ko ^ swz));
      bfrag8 a1 = *(const bfrag8*)(smC + (wm * 64 + 1 * 16 + l15) * 128 + (ko ^ swz));
      bfrag8 a2 = *(const bfrag8*)(smC + (wm * 64 + 2 * 16 + l15) * 128 + (ko ^ swz));
      bfrag8 a3 = *(const bfrag8*)(smC + (wm * 64 + 3 * 16 + l15) * 128 + (ko ^ swz));
      bfrag8 g0 = *(const bfrag8*)(smC + 16384 + (wn * 64 + 0 * 16 + l15) * 128 + (ko ^ swz));
      bfrag8 g1 = *(const bfrag8*)(smC + 16384 + (wn * 64 + 1 * 16 + l15) * 128 + (ko ^ swz));
      bfrag8 g2 = *(const bfrag8*)(smC + 16384 + (wn * 64 + 2 * 16 + l15) * 128 + (ko ^ swz));
      bfrag8 g3 = *(const bfrag8*)(smC + 16384 + (wn * 64 + 3 * 16 + l15) * 128 + (ko ^ swz));
      acc0[0][0] = MFMA16(a0, g0, acc0[0][0]); acc0[0][1] = MFMA16(a0, g1, acc0[0][1]);
      acc0[0][2] = MFMA16(a0, g2, acc0[0][2]); acc0[0][3] = MFMA16(a0, g3, acc0[0][3]);
      acc0[1][0] = MFMA16(a1, g0, acc0[1][0]); acc0[1][1] = MFMA16(a1, g1, acc0[1][1]);
      acc0[1][2] = MFMA16(a1, g2, acc0[1][2]); acc0[1][3] = MFMA16(a1, g3, acc0[1][3]);
      acc0[2][0] = MFMA16(a2, g0, acc0[2][0]); acc0[2][1] = MFMA16(a2, g1, acc0[2][1]);
      acc0[2][2] = MFMA16(a2, g2, acc0[2][2]); acc0[2][3] = MFMA16(a2, g3, acc0[2][3]);
      acc0[3][0] = MFMA16(a3, g0, acc0[3][0]); acc0[3][1] = MFMA16(a3, g1, acc0[3][1]);
      acc0[3][2] = MFMA16(a3, g2, acc0[3][2]); acc0[3][3] = MFMA16(a3, g3, acc0[3][3]);
      bfrag8 u0 = *(const bfrag8*)(smC + 32768 + (wn * 64 + 0 * 16 + l15) * 128 + (ko ^ swz));
      bfrag8 u1 = *(const bfrag8*)(smC + 32768 + (wn * 64 + 1 * 16 + l15) * 128 + (ko ^ swz));
      bfrag8 u2 = *(const bfrag8*)(smC + 32768 + (wn * 64 + 2 * 16 + l15) * 128 + (ko ^ swz));
      bfrag8 u3 = *(const bfrag8*)(smC + 32768 + (wn * 64 + 3 * 16 + l15) * 128 + (ko ^ swz));
      acc1[0][0] = MFMA16(a0, u0, acc1[0][0]); acc1[0][1] = MFMA16(a0, u1, acc1[0][1]);
      acc1[0][2] = MFMA16(a0, u2, acc1[0][2]); acc1[0][3] = MFMA16(a0, u3, acc1[0][3]);
      acc1[1][0] = MFMA16(a1, u0, acc1[1][0]); acc1[1][1] = MFMA16(a1, u1, acc1[1][1]);
      acc1[1][2] = MFMA16(a1, u2, acc1[1][2]); acc1[1][3] = MFMA16(a1, u3, acc1[1][3]);
      acc1[2][0] = MFMA16(a2, u0, acc1[2][0]); acc1[2][1] = MFMA16(a2, u1, acc1[2][1]);
      acc1[2][2] = MFMA16(a2, u2, acc1[2][2]); acc1[2][3] = MFMA16(a2, u3, acc1[2][3]);
      acc1[3][0] = MFMA16(a3, u0, acc1[3][0]); acc1[3][1] = MFMA16(a3, u1, acc1[3][1]);
      acc1[3][2] = MFMA16(a3, u2, acc1[3][2]); acc1[3][3] = MFMA16(a3, u3, acc1[3][3]);
    }
  }

#pragma unroll
  for (int h = 0; h < 2; ++h) {
#pragma unroll
    for (int i = 0; i < 4; ++i) {
#pragma unroll
      for (int j2 = 0; j2 < 4; ++j2) {
        const int mr = m0 + wm * 64 + i * 16 + lhi * 4;
        const int nc = n0 + h * 128 + wn * 64 + j2 * 16 + l15;
#pragma unroll
        for (int r = 0; r < 4; ++r) {
          const size_t idx = (size_t)(mr + r) * N + nc;
          const float v = h ? acc1[i][j2][r] : acc0[i][j2][r];
          if (EPI == 0) {
            outB[idx] = bf_bits(v);
          } else {
            outF[idx] = resid[idx] + v;
          }
        }
      }
    }
  }
}

// ======== fused MLP GEMM: h = up(x) * silu(gate(x)), 128x128 tile (r10/r13) ========
template <int K>
__global__ __launch_bounds__(256, 3) void k_gemm_mlp(const u16* __restrict__ A,
                                                     const u16* __restrict__ Bg,
                                                     const u16* __restrict__ Bu,
                                                     int N,
                                                     u16* __restrict__ outB) {
  __shared__ u16 sm[24576];  // 48 KiB: A | Bg | Bu
  char* smC = (char*)sm;
  const int nbx = gridDim.x;
  const int f = blockIdx.x + nbx * blockIdx.y;
  const int nsl = nbx >> 3;
  const int x = f & 7;
  const int j = f >> 3;
  const int n0 = (x * nsl + (j % nsl)) * 128;
  const int m0 = (j / nsl) * 128;

  const int t = threadIdx.x;
  const int wid = t >> 6, lane = t & 63;
  const int wm = wid >> 1, wn = wid & 1;
  const int l15 = lane & 15, lhi = lane >> 4;
  const int lhi16 = lhi * 16;
  const int swz = (l15 & 7) << 4;

  f32x4 accg[4][4], accu[4][4];
#pragma unroll
  for (int i = 0; i < 4; ++i)
#pragma unroll
    for (int j2 = 0; j2 < 4; ++j2) {
      accg[i][j2] = (f32x4){0.f, 0.f, 0.f, 0.f};
      accu[i][j2] = (f32x4){0.f, 0.f, 0.f, 0.f};
    }

  const int sr = lane >> 3;
  const int csw = (((lane & 7) * 16) ^ (sr << 4)) >> 1;
  const u16* Asrc = A + (size_t)(m0 + wid * 32 + sr) * K + csw;
  const u16* Bgsrc = Bg + (size_t)(n0 + wid * 32 + sr) * K + csw;
  const u16* Busrc = Bu + (size_t)(n0 + wid * 32 + sr) * K + csw;
  char* adst = smC + wid * 4096 + lane * 16;
  char* bgdst = smC + 16384 + wid * 4096 + lane * 16;
  char* budst = smC + 32768 + wid * 4096 + lane * 16;

  for (int kt = 0; kt < K / 64; ++kt) {
    __syncthreads();
    const u16* as = Asrc + kt * 64;
    const u16* gs = Bgsrc + kt * 64;
    const u16* us = Busrc + kt * 64;
#pragma unroll
    for (int c = 0; c < 4; ++c) {
      gload16(as + (size_t)c * 8 * K, adst + c * 1024);
      gload16(gs + (size_t)c * 8 * K, bgdst + c * 1024);
      gload16(us + (size_t)c * 8 * K, budst + c * 1024);
    }
    asm volatile("s_waitcnt vmcnt(0)" ::: "memory");
    __syncthreads();

#pragma unroll
    for (int kh = 0; kh < 2; ++kh) {
      const int ko = (kh * 64 + lhi16);
      bfrag8 a0 = *(const bfrag8*)(smC + (wm * 64 + 0 * 16 + l15) * 128 + (ko ^ swz));
      bfrag8 a1 = *(const bfrag8*)(smC + (wm * 64 + 1 * 16 + l15) * 128 + (ko ^ swz));
      bfrag8 a2 = *(const bfrag8*)(smC + (wm * 64 + 2 * 16 + l15) * 128 + (ko ^ swz));
      bfrag8 a3 = *(const bfrag8*)(smC + (wm * 64 + 3 * 16 + l15) * 128 + (ko ^ swz));
      bfrag8 g0 = *(const bfrag8*)(smC + 16384 + (wn * 64 + 0 * 16 + l15) * 128 + (ko ^ swz));
      bfrag8 g1 = *(const bfrag8*)(smC + 16384 + (wn * 64 + 1 * 16 + l15) * 128 + (ko ^ swz));
      bfrag8 g2 = *(const bfrag8*)(smC + 16384 + (wn * 64 + 2 * 16 + l15) * 128 + (ko ^ swz));
      bfrag8 g3 = *(const bfrag8*)(smC + 16384 + (wn * 64 + 3 * 16 + l15) * 128 + (ko ^ swz));
      accg[0][0] = MFMA16(a0, g0, accg[0][0]); accg[0][1] = MFMA16(a0, g1, accg[0][1]);
      accg[0][2] = MFMA16(a0, g2, accg[0][2]); accg[0][3] = MFMA16(a0, g3, accg[0][3]);
      accg[1][0] = MFMA16(a1, g0, accg[1][0]); accg[1][1] = MFMA16(a1, g1, accg[1][1]);
      accg[1][2] = MFMA16(a1, g2, accg[1][2]); accg[1][3] = MFMA16(a1, g3, accg[1][3]);
      accg[2][0] = MFMA16(a2, g0, accg[2][0]); accg[2][1] = MFMA16(a2, g1, accg[2][1]);
      accg[2][2] = MFMA16(a2, g2, accg[2][2]); accg[2][3] = MFMA16(a2, g3, accg[2][3]);
      accg[3][0] = MFMA16(a3, g0, accg[3][0]); accg[3][1] = MFMA16(a3, g1, accg[3][1]);
      accg[3][2] = MFMA16(a3, g2, accg[3][2]); accg[3][3] = MFMA16(a3, g3, accg[3][3]);
      bfrag8 u0 = *(const bfrag8*)(smC + 32768 + (wn * 64 + 0 * 16 + l15) * 128 + (ko ^ swz));
      bfrag8 u1 = *(const bfrag8*)(smC + 32768 + (wn * 64 + 1 * 16 + l15) * 128 + (ko ^ swz));
      bfrag8 u2 = *(const bfrag8*)(smC + 32768 + (wn * 64 + 2 * 16 + l15) * 128 + (ko ^ swz));
      bfrag8 u3 = *(const bfrag8*)(smC + 32768 + (wn * 64 + 3 * 16 + l15) * 128 + (ko ^ swz));
      accu[0][0] = MFMA16(a0, u0, accu[0][0]); accu[0][1] = MFMA16(a0, u1, accu[0][1]);
      accu[0][2] = MFMA16(a0, u2, accu[0][2]); accu[0][3] = MFMA16(a0, u3, accu[0][3]);
      accu[1][0] = MFMA16(a1, u0, accu[1][0]); accu[1][1] = MFMA16(a1, u1, accu[1][1]);
      accu[1][2] = MFMA16(a1, u2, accu[1][2]); accu[1][3] = MFMA16(a1, u3, accu[1][3]);
      accu[2][0] = MFMA16(a2, u0, accu[2][0]); accu[2][1] = MFMA16(a2, u1, accu[2][1]);
      accu[2][2] = MFMA16(a2, u2, accu[2][2]); accu[2][3] = MFMA16(a2, u3, accu[2][3]);
      accu[3][0] = MFMA16(a3, u0, accu[3][0]); accu[3][1] = MFMA16(a3, u1, accu[3][1]);
      accu[3][2] = MFMA16(a3, u2, accu[3][2]); accu[3][3] = MFMA16(a3, u3, accu[3][3]);
    }
  }

#pragma unroll
  for (int i = 0; i < 4; ++i) {
#pragma unroll
    for (int j2 = 0; j2 < 4; ++j2) {
      const int mr = m0 + wm * 64 + i * 16 + lhi * 4;
      const int nc = n0 + wn * 64 + j2 * 16 + l15;
#pragma unroll
      for (int r = 0; r < 4; ++r) {
        const float g = accg[i][j2][r];
        const float u = accu[i][j2][r];
        const float s = g / (1.f + __expf(-g));
        outB[(size_t)(mr + r) * N + nc] = bf_bits(u * s);
      }
    }
  }
}

// ---------------- causal flash attention (8 waves, QBLK=128, KVBLK=64) ----------------
__global__ __launch_bounds__(512) void k_attn(const u16* __restrict__ qkv,
                                              const u16* __restrict__ vtg,
                                              u16* __restrict__ out) {
  const int S = 2048, LD = 6144;
  const float scale = 0.0883883476483184405f;  // 1/sqrt(128)
  const int fid = blockIdx.x;       // 0..511
  const int p = fid >> 1, s = fid & 1;
  const int bh = p & 31;
  const int pq = p >> 5;            // 0..7
  const int qt = s ? (15 - pq) : pq;
  const int b = bh >> 4, hh = bh & 15;
  const int t = threadIdx.x;
  const int wave = t >> 6, lane = t & 63;
  const int l15 = lane & 15, lhi = lane >> 4;
  const int lhi16 = lhi * 16;
  const int swz = (l15 & 7) << 4;

  __shared__ u16 Kt[64 * 128];
  __shared__ u16 Vt[128 * 64];
  __shared__ u16 Pl[8][16][72];
  char* KtC = (char*)Kt;
  char* VtC = (char*)Vt;

  const int qrow = qt * 128 + wave * 16 + l15;
  const size_t qoff = (size_t)(b * S + qrow) * LD + hh * 128 + lhi * 8;
  bfrag8 qf[4];
#pragma unroll
  for (int ks = 0; ks < 4; ++ks) qf[ks] = *(const bfrag8*)(qkv + qoff + ks * 32);

  f32x4 oacc[8];
#pragma unroll
  for (int j = 0; j < 8; ++j) oacc[j] = (f32x4){0.f, 0.f, 0.f, 0.f};
  float m_i[4], l_i[4];
#pragma unroll
  for (int r = 0; r < 4; ++r) { m_i[r] = -INFINITY; l_i[r] = 0.f; }

  const int q_my = qt * 128 + wave * 16 + lhi * 4;
  const int q_wave_last = qt * 128 + wave * 16 + 15;

  const int keyA = t >> 4, keyB = 32 + (t >> 4);
  const int oK = (t & 15) * 16;
  const int dA = t >> 3, dB = 64 + (t >> 3);
  const int oV = (t & 7) * 16;
  const u16* kbase = qkv + (size_t)(b * S) * LD + 2048 + hh * 128;
  const u16* vbase = vtg + (size_t)bh * 128 * S;
  const u16* ksrcA = kbase + (size_t)keyA * LD + ((oK ^ ((keyA & 7) << 4)) >> 1);
  const u16* ksrcB = kbase + (size_t)keyB * LD + ((oK ^ ((keyB & 7) << 4)) >> 1);
  const u16* vsrcA = vbase + (size_t)dA * S + ((oV ^ ((dA & 7) << 4)) >> 1);
  const u16* vsrcB = vbase + (size_t)dB * S + ((oV ^ ((dB & 7) << 4)) >> 1);
  const unsigned int ldso0 = wave * 1024 + lane * 16;
  const unsigned int ldso1 = 8192 + wave * 1024 + lane * 16;
  const size_t kstep = (size_t)64 * LD;

  const int kt_max = 2 * qt + 1;
  for (int kt = 0; kt <= kt_max; ++kt) {
    __syncthreads();
    gload16(ksrcA + (size_t)kt * kstep, KtC + ldso0);
    gload16(ksrcB + (size_t)kt * kstep, KtC + ldso1);
    gload16(vsrcA + kt * 64, VtC + ldso0);
    gload16(vsrcB + kt * 64, VtC + ldso1);
    __syncthreads();

    if (kt * 64 <= q_wave_last) {
      f32x4 sfr[4];
#pragma unroll
      for (int j = 0; j < 4; ++j) {
        sfr[j] = (f32x4){0.f, 0.f, 0.f, 0.f};
        const int krow = j * 16 + l15;
#pragma unroll
        for (int ks = 0; ks < 4; ++ks) {
          bfrag8 kf = *(const bfrag8*)(KtC + krow * 256 + ((ks * 64 + lhi16) ^ swz));
          sfr[j] = MFMA16(qf[ks], kf, sfr[j]);
        }
      }
      float sv[4][4], rmax[4];
#pragma unroll
      for (int r = 0; r < 4; ++r) rmax[r] = -INFINITY;
#pragma unroll
      for (int j = 0; j < 4; ++j) {
        const int key = kt * 64 + j * 16 + l15;
#pragma unroll
        for (int r = 0; r < 4; ++r) {
          float v = sfr[j][r] * scale;
          v = (key <= q_my + r) ? v : -INFINITY;
          sv[j][r] = v;
          rmax[r] = fmaxf(rmax[r], v);
        }
      }
#pragma unroll
      for (int r = 0; r < 4; ++r) {
        float v = rmax[r];
        v = fmaxf(v, __shfl_xor(v, 1));
        v = fmaxf(v, __shfl_xor(v, 2));
        v = fmaxf(v, __shfl_xor(v, 4));
        v = fmaxf(v, __shfl_xor(v, 8));
        rmax[r] = v;
      }
      float alpha[4], rsum[4];
#pragma unroll
      for (int r = 0; r < 4; ++r) {
        float mn = fmaxf(m_i[r], rmax[r]);
        alpha[r] = __expf(m_i[r] - mn);
        m_i[r] = mn;
        rsum[r] = 0.f;
      }
#pragma unroll
      for (int j = 0; j < 4; ++j) {
#pragma unroll
        for (int r = 0; r < 4; ++r) {
          float p2 = __expf(sv[j][r] - m_i[r]);
          rsum[r] += p2;
          Pl[wave][lhi * 4 + r][j * 16 + l15] = bf_bits(p2);
        }
      }
#pragma unroll
      for (int r = 0; r < 4; ++r) {
        float v = rsum[r];
        v += __shfl_xor(v, 1); v += __shfl_xor(v, 2);
        v += __shfl_xor(v, 4); v += __shfl_xor(v, 8);
        l_i[r] = l_i[r] * alpha[r] + v;
      }
#pragma unroll
      for (int j = 0; j < 8; ++j)
#pragma unroll
        for (int r = 0; r < 4; ++r) oacc[j][r] *= alpha[r];

#pragma unroll
      for (int ks2 = 0; ks2 < 2; ++ks2) {
        bfrag8 pf = *(const bfrag8*)&Pl[wave][l15][ks2 * 32 + lhi * 8];
#pragma unroll
        for (int j = 0; j < 8; ++j) {
          const int d = j * 16 + l15;
          bfrag8 vf = *(const bfrag8*)(VtC + d * 128 + ((ks2 * 64 + lhi16) ^ swz));
          oacc[j] = MFMA16(pf, vf, oacc[j]);
        }
      }
    }
  }

#pragma unroll
  for (int r = 0; r < 4; ++r) {
    const float inv = 1.f / l_i[r];
    const size_t tok = (size_t)b * S + qt * 128 + wave * 16 + lhi * 4 + r;
#pragma unroll
    for (int j = 0; j < 8; ++j)
      out[tok * 2048 + hh * 128 + j * 16 + l15] = bf_bits(oacc[j][r] * inv);
  }
}

// ---------------- launch ----------------
extern "C" void kernel_launch(void* const* d_in, const int* in_sizes, int n_in,
                              void* d_out, int out_size, void* d_ws, size_t ws_size,
                              hipStream_t stream) {
  (void)in_sizes; (void)n_in; (void)out_size; (void)ws_size;
  const float* x      = (const float*)d_in[0];
  const float* w_qkv  = (const float*)d_in[1];
  const float* w_o    = (const float*)d_in[2];
  const float* w_up   = (const float*)d_in[3];
  const float* w_gate = (const float*)d_in[4];
  const float* w_down = (const float*)d_in[5];
  const float* scale1 = (const float*)d_in[6];
  const float* scale2 = (const float*)d_in[7];
  float* out = (float*)d_out;

  u16* B       = (u16*)d_ws;
  u16* wqkvT   = B;                               // [6144][2048]
  u16* woT     = wqkvT  + (size_t)6144 * 2048;    // [2048][2048]
  u16* wgateT  = woT    + (size_t)2048 * 2048;    // [8192][2048]
  u16* wupT    = wgateT + (size_t)8192 * 2048;    // [8192][2048]
  u16* wdownT  = wupT   + (size_t)8192 * 2048;    // [2048][8192]
  u16* xn      = wdownT + (size_t)2048 * 8192;    // [4096][2048]
  u16* qkvb    = xn     + (size_t)4096 * 2048;    // [4096][6144]
  u16* attnb   = qkvb   + (size_t)4096 * 6144;    // [4096][2048]
  float* y1    = (float*)(attnb + (size_t)4096 * 2048);  // [4096][2048] f32
  u16* vtg     = (u16*)y1;   // alias: vtg dead before y1 written
  u16* hbuf    = qkvb;       // alias: qkv+attn dead after out-proj (4096*8192 exact)

  dim3 blk(256);
  k_transpose_bf16<<<dim3(192, 64), blk, 0, stream>>>(w_qkv,  wqkvT,  2048, 6144);
  k_transpose_bf16<<<dim3(64, 64),  blk, 0, stream>>>(w_o,    woT,    2048, 2048);
  k_transpose_bf16<<<dim3(256, 64), blk, 0, stream>>>(w_gate, wgateT, 2048, 8192);
  k_transpose_bf16<<<dim3(256, 64), blk, 0, stream>>>(w_up,   wupT,   2048, 8192);
  k_transpose_bf16<<<dim3(64, 256), blk, 0, stream>>>(w_down, wdownT, 8192, 2048);

  k_rmsnorm<<<4096, blk, 0, stream>>>(x, scale1, xn);
  k_gemm2<0, 2048, 0><<<dim3(24, 32), blk, 0, stream>>>(xn, wqkvT, 6144, nullptr, qkvb, nullptr);
  k_transpose_v<<<dim3(64, 4, 32), blk, 0, stream>>>(qkvb, vtg);
  k_attn<<<dim3(512), dim3(512), 0, stream>>>(qkvb, vtg, attnb);
  k_gemm<1, 2048, 1><<<dim3(16, 32), blk, 0, stream>>>(attnb, woT, 4096, 2048, y1, nullptr, x, nullptr);
  k_rmsnorm<<<4096, blk, 0, stream>>>(y1, scale2, xn);
  k_gemm_mlp<2048><<<dim3(64, 32), blk, 0, stream>>>(xn, wgateT, wupT, 8192, hbuf);
  k_gemm<1, 8192, 1><<<dim3(16, 32), blk, 0, stream>>>(hbuf, wdownT, 4096, 2048, out, nullptr, y1, nullptr);
}

// Round 18
// 816.250 us; speedup vs baseline: 1.0185x; 1.0033x over previous
//
#include <hip/hip_runtime.h>

typedef unsigned short u16;
typedef __bf16 bfrag8 __attribute__((ext_vector_type(8)));
typedef float f32x4 __attribute__((ext_vector_type(4)));

#define MFMA16(a, b, c) __builtin_amdgcn_mfma_f32_16x16x32_bf16((a), (b), (c), 0, 0, 0)

static __device__ __forceinline__ u16 bf_bits(float f) {
  unsigned int u = __builtin_bit_cast(unsigned int, f);
  unsigned int r = (u + 0x7fffu + ((u >> 16) & 1u)) >> 16;
  return (u16)r;
}
static __device__ __forceinline__ float f_from_bits(u16 u) {
  unsigned int w = ((unsigned int)u) << 16;
  return __builtin_bit_cast(float, w);
}
static __device__ __forceinline__ void gload16(const void* g, void* l) {
  __builtin_amdgcn_global_load_lds(
      (const __attribute__((address_space(1))) void*)g,
      (__attribute__((address_space(3))) void*)l, 16, 0, 0);
}

// ---------------- transpose f32 [K][N] -> bf16 [N][K] ----------------
__global__ __launch_bounds__(256) void k_transpose_bf16(const float* __restrict__ src,
                                                        u16* __restrict__ dst,
                                                        int K, int N) {
  __shared__ float tile[32][33];
  const int n0 = blockIdx.x * 32;
  const int k0 = blockIdx.y * 32;
  const int t = threadIdx.x;
  const int lr = t >> 5;
  const int lc = t & 31;
#pragma unroll
  for (int i = 0; i < 4; ++i)
    tile[lr + i * 8][lc] = src[(size_t)(k0 + lr + i * 8) * N + n0 + lc];
  __syncthreads();
#pragma unroll
  for (int i = 0; i < 4; ++i)
    dst[(size_t)(n0 + lr + i * 8) * K + k0 + lc] = bf_bits(tile[lc][lr + i * 8]);
}

// ---------------- transpose V out of qkv: -> vtg[bh][128 d][2048 tok] ----------------
__global__ __launch_bounds__(256) void k_transpose_v(const u16* __restrict__ qkv,
                                                     u16* __restrict__ vtg) {
  __shared__ u16 tile[32][33];
  const int bh = blockIdx.z, b = bh >> 4, hh = bh & 15;
  const int s0 = blockIdx.x * 32, d0 = blockIdx.y * 32;
  const int t = threadIdx.x;
  const int lr = t >> 5, lc = t & 31;
#pragma unroll
  for (int i = 0; i < 4; ++i)
    tile[lr + i * 8][lc] =
        qkv[(size_t)(b * 2048 + s0 + lr + i * 8) * 6144 + 4096 + hh * 128 + d0 + lc];
  __syncthreads();
#pragma unroll
  for (int i = 0; i < 4; ++i)
    vtg[(size_t)bh * 128 * 2048 + (size_t)(d0 + lr + i * 8) * 2048 + s0 + lc] =
        tile[lc][lr + i * 8];
}

// ---------------- rmsnorm: f32 [rows][2048] -> bf16 ----------------
__global__ __launch_bounds__(256) void k_rmsnorm(const float* __restrict__ x,
                                                 const float* __restrict__ sc,
                                                 u16* __restrict__ o) {
  const int row = blockIdx.x;
  const int t = threadIdx.x;
  const float4* x4 = (const float4*)(x + (size_t)row * 2048);
  float4 a = x4[t];
  float4 b = x4[t + 256];
  float ss = a.x * a.x + a.y * a.y + a.z * a.z + a.w * a.w +
             b.x * b.x + b.y * b.y + b.z * b.z + b.w * b.w;
#pragma unroll
  for (int off = 32; off > 0; off >>= 1) ss += __shfl_down(ss, off);
  __shared__ float red[4];
  if ((t & 63) == 0) red[t >> 6] = ss;
  __syncthreads();
  const float inv = rsqrtf((red[0] + red[1] + red[2] + red[3]) * (1.0f / 2048.0f) + 1e-6f);
  const float4* s4 = (const float4*)sc;
  float4 sa = s4[t], sb = s4[t + 256];
  ushort4 pa, pb;
  pa.x = bf_bits(a.x * inv * sa.x); pa.y = bf_bits(a.y * inv * sa.y);
  pa.z = bf_bits(a.z * inv * sa.z); pa.w = bf_bits(a.w * inv * sa.w);
  pb.x = bf_bits(b.x * inv * sb.x); pb.y = bf_bits(b.y * inv * sb.y);
  pb.z = bf_bits(b.z * inv * sb.z); pb.w = bf_bits(b.w * inv * sb.w);
  *(ushort4*)(o + (size_t)row * 2048 + t * 4) = pa;
  *(ushort4*)(o + (size_t)row * 2048 + (t + 256) * 4) = pb;
}

// ---------------- combine3: out = out + p0 + p1 + resid (all f32) ----------------
__global__ __launch_bounds__(256) void k_combine3(float* __restrict__ out,
                                                  const float* __restrict__ p0,
                                                  const float* __restrict__ p1,
                                                  const float* __restrict__ resid) {
  const size_t i = ((size_t)blockIdx.x * 256 + threadIdx.x) * 4;
  float4 o = *(const float4*)(out + i);
  float4 a = *(const float4*)(p0 + i);
  float4 b = *(const float4*)(p1 + i);
  float4 r = *(const float4*)(resid + i);
  o.x += a.x + b.x + r.x; o.y += a.y + b.y + r.y;
  o.z += a.z + b.z + r.z; o.w += a.w + b.w + r.w;
  *(float4*)(out + i) = o;
}

// ======== 128x128 GEMM, 4 waves (64x64 wave tile), 4 blocks/CU (r12) ========
template <int EPI, int K, int PART>
__global__ __launch_bounds__(256, 4) void k_gemm(const u16* __restrict__ A,
                                                 const u16* __restrict__ Bt,
                                                 int M, int N,
                                                 float* __restrict__ outF,
                                                 u16* __restrict__ outB,
                                                 const float* __restrict__ resid,
                                                 const u16* __restrict__ gate) {
  __shared__ u16 sm[16384];  // 32 KiB: A | B
  char* smC = (char*)sm;
  const int nbx = gridDim.x;
  const int f = blockIdx.x + nbx * blockIdx.y;
  int m0, n0;
  if (PART == 0) {
    const int nsl = nbx >> 3;
    const int x = f & 7;
    const int j = f >> 3;
    n0 = (x * nsl + (j % nsl)) * 128;
    m0 = (j / nsl) * 128;
  } else {
    const int msl = (int)gridDim.y >> 3;
    const int x = f & 7;
    const int j = f >> 3;
    m0 = (x * msl + (j % msl)) * 128;
    n0 = (j / msl) * 128;
  }

  const int t = threadIdx.x;
  const int wid = t >> 6, lane = t & 63;
  const int wm = wid >> 1, wn = wid & 1;
  const int l15 = lane & 15, lhi = lane >> 4;
  const int lhi16 = lhi * 16;
  const int swz = (l15 & 7) << 4;

  f32x4 acc[4][4];
#pragma unroll
  for (int i = 0; i < 4; ++i)
#pragma unroll
    for (int j2 = 0; j2 < 4; ++j2) acc[i][j2] = (f32x4){0.f, 0.f, 0.f, 0.f};

  const int sr = lane >> 3;
  const int csw = (((lane & 7) * 16) ^ (sr << 4)) >> 1;
  const u16* Asrc = A + (size_t)(m0 + wid * 32 + sr) * K + csw;
  const u16* Bsrc = Bt + (size_t)(n0 + wid * 32 + sr) * K + csw;
  char* adst = smC + wid * 4096 + lane * 16;
  char* bdst = smC + 16384 + wid * 4096 + lane * 16;

  for (int kt = 0; kt < K / 64; ++kt) {
    __syncthreads();
    const u16* as = Asrc + kt * 64;
    const u16* bs = Bsrc + kt * 64;
#pragma unroll
    for (int c = 0; c < 4; ++c) {
      gload16(as + (size_t)c * 8 * K, adst + c * 1024);
      gload16(bs + (size_t)c * 8 * K, bdst + c * 1024);
    }
    asm volatile("s_waitcnt vmcnt(0)" ::: "memory");
    __syncthreads();

#pragma unroll
    for (int kh = 0; kh < 2; ++kh) {
      const int ko = kh * 64 + lhi16;
      bfrag8 a0 = *(const bfrag8*)(smC + (wm * 64 + 0 * 16 + l15) * 128 + (ko ^ swz));
      bfrag8 a1 = *(const bfrag8*)(smC + (wm * 64 + 1 * 16 + l15) * 128 + (ko ^ swz));
      bfrag8 a2 = *(const bfrag8*)(smC + (wm * 64 + 2 * 16 + l15) * 128 + (ko ^ swz));
      bfrag8 a3 = *(const bfrag8*)(smC + (wm * 64 + 3 * 16 + l15) * 128 + (ko ^ swz));
      bfrag8 b0 = *(const bfrag8*)(smC + 16384 + (wn * 64 + 0 * 16 + l15) * 128 + (ko ^ swz));
      bfrag8 b1 = *(const bfrag8*)(smC + 16384 + (wn * 64 + 1 * 16 + l15) * 128 + (ko ^ swz));
      bfrag8 b2 = *(const bfrag8*)(smC + 16384 + (wn * 64 + 2 * 16 + l15) * 128 + (ko ^ swz));
      bfrag8 b3 = *(const bfrag8*)(smC + 16384 + (wn * 64 + 3 * 16 + l15) * 128 + (ko ^ swz));
      acc[0][0] = MFMA16(a0, b0, acc[0][0]); acc[0][1] = MFMA16(a0, b1, acc[0][1]);
      acc[0][2] = MFMA16(a0, b2, acc[0][2]); acc[0][3] = MFMA16(a0, b3, acc[0][3]);
      acc[1][0] = MFMA16(a1, b0, acc[1][0]); acc[1][1] = MFMA16(a1, b1, acc[1][1]);
      acc[1][2] = MFMA16(a1, b2, acc[1][2]); acc[1][3] = MFMA16(a1, b3, acc[1][3]);
      acc[2][0] = MFMA16(a2, b0, acc[2][0]); acc[2][1] = MFMA16(a2, b1, acc[2][1]);
      acc[2][2] = MFMA16(a2, b2, acc[2][2]); acc[2][3] = MFMA16(a2, b3, acc[2][3]);
      acc[3][0] = MFMA16(a3, b0, acc[3][0]); acc[3][1] = MFMA16(a3, b1, acc[3][1]);
      acc[3][2] = MFMA16(a3, b2, acc[3][2]); acc[3][3] = MFMA16(a3, b3, acc[3][3]);
    }
  }

#pragma unroll
  for (int i = 0; i < 4; ++i) {
#pragma unroll
    for (int j2 = 0; j2 < 4; ++j2) {
      const int mr = m0 + wm * 64 + i * 16 + lhi * 4;
      const int nc = n0 + wn * 64 + j2 * 16 + l15;
#pragma unroll
      for (int r = 0; r < 4; ++r) {
        const size_t idx = (size_t)(mr + r) * N + nc;
        const float v = acc[i][j2][r];
        if (EPI == 0) {
          outB[idx] = bf_bits(v);
        } else if (EPI == 1) {
          outF[idx] = resid[idx] + v;
        } else {
          float g = f_from_bits(gate[idx]);
          float s = g / (1.f + __expf(-g));
          outB[idx] = bf_bits(v * s);
        }
      }
    }
  }
}

// ======== 128x256 dual-n GEMM (qkv: 768 blocks = 3/CU exact) ========
template <int EPI, int K, int PART>
__global__ __launch_bounds__(256, 3) void k_gemm2(const u16* __restrict__ A,
                                                  const u16* __restrict__ Bt,
                                                  int N,
                                                  float* __restrict__ outF,
                                                  u16* __restrict__ outB,
                                                  const float* __restrict__ resid) {
  __shared__ u16 sm[24576];  // 48 KiB: A | B0 | B1
  char* smC = (char*)sm;
  const int nbx = gridDim.x;  // n-pairs
  const int f = blockIdx.x + nbx * blockIdx.y;
  int m0, np;
  if (PART == 0) {
    const int nsl = nbx >> 3;
    const int x = f & 7;
    const int j = f >> 3;
    np = x * nsl + (j % nsl);
    m0 = (j / nsl) * 128;
  } else {
    const int msl = (int)gridDim.y >> 3;
    const int x = f & 7;
    const int j = f >> 3;
    m0 = (x * msl + (j % msl)) * 128;
    np = j / msl;
  }
  const int n0 = np * 256;

  const int t = threadIdx.x;
  const int wid = t >> 6, lane = t & 63;
  const int wm = wid >> 1, wn = wid & 1;
  const int l15 = lane & 15, lhi = lane >> 4;
  const int lhi16 = lhi * 16;
  const int swz = (l15 & 7) << 4;

  f32x4 acc0[4][4], acc1[4][4];
#pragma unroll
  for (int i = 0; i < 4; ++i)
#pragma unroll
    for (int j2 = 0; j2 < 4; ++j2) {
      acc0[i][j2] = (f32x4){0.f, 0.f, 0.f, 0.f};
      acc1[i][j2] = (f32x4){0.f, 0.f, 0.f, 0.f};
    }

  const int sr = lane >> 3;
  const int csw = (((lane & 7) * 16) ^ (sr << 4)) >> 1;
  const u16* Asrc = A + (size_t)(m0 + wid * 32 + sr) * K + csw;
  const u16* B0src = Bt + (size_t)(n0 + wid * 32 + sr) * K + csw;
  const u16* B1src = Bt + (size_t)(n0 + 128 + wid * 32 + sr) * K + csw;
  char* adst = smC + wid * 4096 + lane * 16;
  char* b0dst = smC + 16384 + wid * 4096 + lane * 16;
  char* b1dst = smC + 32768 + wid * 4096 + lane * 16;

  for (int kt = 0; kt < K / 64; ++kt) {
    __syncthreads();
    const u16* as = Asrc + kt * 64;
    const u16* b0s = B0src + kt * 64;
    const u16* b1s = B1src + kt * 64;
#pragma unroll
    for (int c = 0; c < 4; ++c) {
      gload16(as + (size_t)c * 8 * K, adst + c * 1024);
      gload16(b0s + (size_t)c * 8 * K, b0dst + c * 1024);
      gload16(b1s + (size_t)c * 8 * K, b1dst + c * 1024);
    }
    asm volatile("s_waitcnt vmcnt(0)" ::: "memory");
    __syncthreads();

#pragma unroll
    for (int kh = 0; kh < 2; ++kh) {
      const int ko = (kh * 64 + lhi16);
      bfrag8 a0 = *(const bfrag8*)(smC + (wm * 64 + 0 * 16 + l15) * 128 + (ko ^ swz));
      bfrag8 a1 = *(const bfrag8*)(smC + (wm * 64 + 1 * 16 + l15) * 128 + (ko ^ swz));
      bfrag8 a2 = *(const bfrag8*)(smC + (wm * 64 + 2 * 16 + l15) * 128 + (ko ^ swz));
      bfrag8 a3 = *(const bfrag8*)(smC + (wm * 64 + 3 * 16 + l15) * 128 + (ko ^ swz));
      bfrag8 g0 = *(const bfrag8*)(smC + 16384 + (wn * 64 + 0 * 16 + l15) * 128 + (ko ^ swz));
      bfrag8 g1 = *(const bfrag8*)(smC + 16384 + (wn * 64 + 1 * 16 + l15) * 128 + (ko ^ swz));
      bfrag8 g2 = *(const bfrag8*)(smC + 16384 + (wn * 64 + 2 * 16 + l15) * 128 + (ko ^ swz));
      bfrag8 g3 = *(const bfrag8*)(smC + 16384 + (wn * 64 + 3 * 16 + l15) * 128 + (ko ^ swz));
      acc0[0][0] = MFMA16(a0, g0, acc0[0][0]); acc0[0][1] = MFMA16(a0, g1, acc0[0][1]);
      acc0[0][2] = MFMA16(a0, g2, acc0[0][2]); acc0[0][3] = MFMA16(a0, g3, acc0[0][3]);
      acc0[1][0] = MFMA16(a1, g0, acc0[1][0]); acc0[1][1] = MFMA16(a1, g1, acc0[1][1]);
      acc0[1][2] = MFMA16(a1, g2, acc0[1][2]); acc0[1][3] = MFMA16(a1, g3, acc0[1][3]);
      acc0[2][0] = MFMA16(a2, g0, acc0[2][0]); acc0[2][1] = MFMA16(a2, g1, acc0[2][1]);
      acc0[2][2] = MFMA16(a2, g2, acc0[2][2]); acc0[2][3] = MFMA16(a2, g3, acc0[2][3]);
      acc0[3][0] = MFMA16(a3, g0, acc0[3][0]); acc0[3][1] = MFMA16(a3, g1, acc0[3][1]);
      acc0[3][2] = MFMA16(a3, g2, acc0[3][2]); acc0[3][3] = MFMA16(a3, g3, acc0[3][3]);
      bfrag8 u0 = *(const bfrag8*)(smC + 32768 + (wn * 64 + 0 * 16 + l15) * 128 + (ko ^ swz));
      bfrag8 u1 = *(const bfrag8*)(smC + 32768 + (wn * 64 + 1 * 16 + l15) * 128 + (ko ^ swz));
      bfrag8 u2 = *(const bfrag8*)(smC + 32768 + (wn * 64 + 2 * 16 + l15) * 128 + (ko ^ swz));
      bfrag8 u3 = *(const bfrag8*)(smC + 32768 + (wn * 64 + 3 * 16 + l15) * 128 + (ko ^ swz));
      acc1[0][0] = MFMA16(a0, u0, acc1[0][0]); acc1[0][1] = MFMA16(a0, u1, acc1[0][1]);
      acc1[0][2] = MFMA16(a0, u2, acc1[0][2]); acc1[0][3] = MFMA16(a0, u3, acc1[0][3]);
      acc1[1][0] = MFMA16(a1, u0, acc1[1][0]); acc1[1][1] = MFMA16(a1, u1, acc1[1][1]);
      acc1[1][2] = MFMA16(a1, u2, acc1[1][2]); acc1[1][3] = MFMA16(a1, u3, acc1[1][3]);
      acc1[2][0] = MFMA16(a2, u0, acc1[2][0]); acc1[2][1] = MFMA16(a2, u1, acc1[2][1]);
      acc1[2][2] = MFMA16(a2, u2, acc1[2][2]); acc1[2][3] = MFMA16(a2, u3, acc1[2][3]);
      acc1[3][0] = MFMA16(a3, u0, acc1[3][0]); acc1[3][1] = MFMA16(a3, u1, acc1[3][1]);
      acc1[3][2] = MFMA16(a3, u2, acc1[3][2]); acc1[3][3] = MFMA16(a3, u3, acc1[3][3]);
    }
  }

#pragma unroll
  for (int h = 0; h < 2; ++h) {
#pragma unroll
    for (int i = 0; i < 4; ++i) {
#pragma unroll
      for (int j2 = 0; j2 < 4; ++j2) {
        const int mr = m0 + wm * 64 + i * 16 + lhi * 4;
        const int nc = n0 + h * 128 + wn * 64 + j2 * 16 + l15;
#pragma unroll
        for (int r = 0; r < 4; ++r) {
          const size_t idx = (size_t)(mr + r) * N + nc;
          const float v = h ? acc1[i][j2][r] : acc0[i][j2][r];
          if (EPI == 0) {
            outB[idx] = bf_bits(v);
          } else {
            outF[idx] = resid[idx] + v;
          }
        }
      }
    }
  }
}

// ======== split-K x3 dual-n GEMM for down (768 blocks = 3/CU) ========
// z in [0,3): K-window z*2752 .. +{2752,2752,2688}. Raw f32 partials to
// p0/p1/out; combine3 folds them + residual. r15/r16/r14 established the
// dual-n structure needs exactly >=3 blocks/CU — this grid provides it.
template <int K>
__global__ __launch_bounds__(256, 3) void k_gemm2s(const u16* __restrict__ A,
                                                   const u16* __restrict__ Bt,
                                                   int N,
                                                   float* __restrict__ p0,
                                                   float* __restrict__ p1,
                                                   float* __restrict__ p2) {
  __shared__ u16 sm[24576];  // 48 KiB: A | B0 | B1
  char* smC = (char*)sm;
  const int nbx = gridDim.x;  // n-pairs
  const int f = blockIdx.x + nbx * blockIdx.y;
  const int z = blockIdx.z;
  const int msl = (int)gridDim.y >> 3;   // PART=1 m-slice mapping
  const int x = f & 7;
  const int j = f >> 3;
  const int m0 = (x * msl + (j % msl)) * 128;
  const int np = j / msl;
  const int n0 = np * 256;
  const int koff = z * 2752;             // 43 k-tiles per slice (last: 42)
  const int ktn = (z == 2) ? 42 : 43;

  const int t = threadIdx.x;
  const int wid = t >> 6, lane = t & 63;
  const int wm = wid >> 1, wn = wid & 1;
  const int l15 = lane & 15, lhi = lane >> 4;
  const int lhi16 = lhi * 16;
  const int swz = (l15 & 7) << 4;

  f32x4 acc0[4][4], acc1[4][4];
#pragma unroll
  for (int i = 0; i < 4; ++i)
#pragma unroll
    for (int j2 = 0; j2 < 4; ++j2) {
      acc0[i][j2] = (f32x4){0.f, 0.f, 0.f, 0.f};
      acc1[i][j2] = (f32x4){0.f, 0.f, 0.f, 0.f};
    }

  const int sr = lane >> 3;
  const int csw = (((lane & 7) * 16) ^ (sr << 4)) >> 1;
  const u16* Asrc = A + (size_t)(m0 + wid * 32 + sr) * K + csw + koff;
  const u16* B0src = Bt + (size_t)(n0 + wid * 32 + sr) * K + csw + koff;
  const u16* B1src = Bt + (size_t)(n0 + 128 + wid * 32 + sr) * K + csw + koff;
  char* adst = smC + wid * 4096 + lane * 16;
  char* b0dst = smC + 16384 + wid * 4096 + lane * 16;
  char* b1dst = smC + 32768 + wid * 4096 + lane * 16;

  for (int kt = 0; kt < ktn; ++kt) {
    __syncthreads();
    const u16* as = Asrc + kt * 64;
    const u16* b0s = B0src + kt * 64;
    const u16* b1s = B1src + kt * 64;
#pragma unroll
    for (int c = 0; c < 4; ++c) {
      gload16(as + (size_t)c * 8 * K, adst + c * 1024);
      gload16(b0s + (size_t)c * 8 * K, b0dst + c * 1024);
      gload16(b1s + (size_t)c * 8 * K, b1dst + c * 1024);
    }
    asm volatile("s_waitcnt vmcnt(0)" ::: "memory");
    __syncthreads();

#pragma unroll
    for (int kh = 0; kh < 2; ++kh) {
      const int ko = (kh * 64 + lhi16);
      bfrag8 a0 = *(const bfrag8*)(smC + (wm * 64 + 0 * 16 + l15) * 128 + (ko ^ swz));
      bfrag8 a1 = *(const bfrag8*)(smC + (wm * 64 + 1 * 16 + l15) * 128 + (ko ^ swz));
      bfrag8 a2 = *(const bfrag8*)(smC + (wm * 64 + 2 * 16 + l15) * 128 + (ko ^ swz));
      bfrag8 a3 = *(const bfrag8*)(smC + (wm * 64 + 3 * 16 + l15) * 128 + (ko ^ swz));
      bfrag8 g0 = *(const bfrag8*)(smC + 16384 + (wn * 64 + 0 * 16 + l15) * 128 + (ko ^ swz));
      bfrag8 g1 = *(const bfrag8*)(smC + 16384 + (wn * 64 + 1 * 16 + l15) * 128 + (ko ^ swz));
      bfrag8 g2 = *(const bfrag8*)(smC + 16384 + (wn * 64 + 2 * 16 + l15) * 128 + (ko ^ swz));
      bfrag8 g3 = *(const bfrag8*)(smC + 16384 + (wn * 64 + 3 * 16 + l15) * 128 + (ko ^ swz));
      acc0[0][0] = MFMA16(a0, g0, acc0[0][0]); acc0[0][1] = MFMA16(a0, g1, acc0[0][1]);
      acc0[0][2] = MFMA16(a0, g2, acc0[0][2]); acc0[0][3] = MFMA16(a0, g3, acc0[0][3]);
      acc0[1][0] = MFMA16(a1, g0, acc0[1][0]); acc0[1][1] = MFMA16(a1, g1, acc0[1][1]);
      acc0[1][2] = MFMA16(a1, g2, acc0[1][2]); acc0[1][3] = MFMA16(a1, g3, acc0[1][3]);
      acc0[2][0] = MFMA16(a2, g0, acc0[2][0]); acc0[2][1] = MFMA16(a2, g1, acc0[2][1]);
      acc0[2][2] = MFMA16(a2, g2, acc0[2][2]); acc0[2][3] = MFMA16(a2, g3, acc0[2][3]);
      acc0[3][0] = MFMA16(a3, g0, acc0[3][0]); acc0[3][1] = MFMA16(a3, g1, acc0[3][1]);
      acc0[3][2] = MFMA16(a3, g2, acc0[3][2]); acc0[3][3] = MFMA16(a3, g3, acc0[3][3]);
      bfrag8 u0 = *(const bfrag8*)(smC + 32768 + (wn * 64 + 0 * 16 + l15) * 128 + (ko ^ swz));
      bfrag8 u1 = *(const bfrag8*)(smC + 32768 + (wn * 64 + 1 * 16 + l15) * 128 + (ko ^ swz));
      bfrag8 u2 = *(const bfrag8*)(smC + 32768 + (wn * 64 + 2 * 16 + l15) * 128 + (ko ^ swz));
      bfrag8 u3 = *(const bfrag8*)(smC + 32768 + (wn * 64 + 3 * 16 + l15) * 128 + (ko ^ swz));
      acc1[0][0] = MFMA16(a0, u0, acc1[0][0]); acc1[0][1] = MFMA16(a0, u1, acc1[0][1]);
      acc1[0][2] = MFMA16(a0, u2, acc1[0][2]); acc1[0][3] = MFMA16(a0, u3, acc1[0][3]);
      acc1[1][0] = MFMA16(a1, u0, acc1[1][0]); acc1[1][1] = MFMA16(a1, u1, acc1[1][1]);
      acc1[1][2] = MFMA16(a1, u2, acc1[1][2]); acc1[1][3] = MFMA16(a1, u3, acc1[1][3]);
      acc1[2][0] = MFMA16(a2, u0, acc1[2][0]); acc1[2][1] = MFMA16(a2, u1, acc1[2][1]);
      acc1[2][2] = MFMA16(a2, u2, acc1[2][2]); acc1[2][3] = MFMA16(a2, u3, acc1[2][3]);
      acc1[3][0] = MFMA16(a3, u0, acc1[3][0]); acc1[3][1] = MFMA16(a3, u1, acc1[3][1]);
      acc1[3][2] = MFMA16(a3, u2, acc1[3][2]); acc1[3][3] = MFMA16(a3, u3, acc1[3][3]);
    }
  }

  float* wout = (z == 0) ? p0 : ((z == 1) ? p1 : p2);
#pragma unroll
  for (int h = 0; h < 2; ++h) {
#pragma unroll
    for (int i = 0; i < 4; ++i) {
#pragma unroll
      for (int j2 = 0; j2 < 4; ++j2) {
        const int mr = m0 + wm * 64 + i * 16 + lhi * 4;
        const int nc = n0 + h * 128 + wn * 64 + j2 * 16 + l15;
#pragma unroll
        for (int r = 0; r < 4; ++r) {
          const size_t idx = (size_t)(mr + r) * N + nc;
          wout[idx] = h ? acc1[i][j2][r] : acc0[i][j2][r];
        }
      }
    }
  }
}

// ======== fused MLP GEMM: h = up(x) * silu(gate(x)), 128x128 tile (r10/r13) ========
template <int K>
__global__ __launch_bounds__(256, 3) void k_gemm_mlp(const u16* __restrict__ A,
                                                     const u16* __restrict__ Bg,
                                                     const u16* __restrict__ Bu,
                                                     int N,
                                                     u16* __restrict__ outB) {
  __shared__ u16 sm[24576];  // 48 KiB: A | Bg | Bu
  char* smC = (char*)sm;
  const int nbx = gridDim.x;
  const int f = blockIdx.x + nbx * blockIdx.y;
  const int nsl = nbx >> 3;
  const int x = f & 7;
  const int j = f >> 3;
  const int n0 = (x * nsl + (j % nsl)) * 128;
  const int m0 = (j / nsl) * 128;

  const int t = threadIdx.x;
  const int wid = t >> 6, lane = t & 63;
  const int wm = wid >> 1, wn = wid & 1;
  const int l15 = lane & 15, lhi = lane >> 4;
  const int lhi16 = lhi * 16;
  const int swz = (l15 & 7) << 4;

  f32x4 accg[4][4], accu[4][4];
#pragma unroll
  for (int i = 0; i < 4; ++i)
#pragma unroll
    for (int j2 = 0; j2 < 4; ++j2) {
      accg[i][j2] = (f32x4){0.f, 0.f, 0.f, 0.f};
      accu[i][j2] = (f32x4){0.f, 0.f, 0.f, 0.f};
    }

  const int sr = lane >> 3;
  const int csw = (((lane & 7) * 16) ^ (sr << 4)) >> 1;
  const u16* Asrc = A + (size_t)(m0 + wid * 32 + sr) * K + csw;
  const u16* Bgsrc = Bg + (size_t)(n0 + wid * 32 + sr) * K + csw;
  const u16* Busrc = Bu + (size_t)(n0 + wid * 32 + sr) * K + csw;
  char* adst = smC + wid * 4096 + lane * 16;
  char* bgdst = smC + 16384 + wid * 4096 + lane * 16;
  char* budst = smC + 32768 + wid * 4096 + lane * 16;

  for (int kt = 0; kt < K / 64; ++kt) {
    __syncthreads();
    const u16* as = Asrc + kt * 64;
    const u16* gs = Bgsrc + kt * 64;
    const u16* us = Busrc + kt * 64;
#pragma unroll
    for (int c = 0; c < 4; ++c) {
      gload16(as + (size_t)c * 8 * K, adst + c * 1024);
      gload16(gs + (size_t)c * 8 * K, bgdst + c * 1024);
      gload16(us + (size_t)c * 8 * K, budst + c * 1024);
    }
    asm volatile("s_waitcnt vmcnt(0)" ::: "memory");
    __syncthreads();

#pragma unroll
    for (int kh = 0; kh < 2; ++kh) {
      const int ko = (kh * 64 + lhi16);
      bfrag8 a0 = *(const bfrag8*)(smC + (wm * 64 + 0 * 16 + l15) * 128 + (ko ^ swz));
      bfrag8 a1 = *(const bfrag8*)(smC + (wm * 64 + 1 * 16 + l15) * 128 + (ko ^ swz));
      bfrag8 a2 = *(const bfrag8*)(smC + (wm * 64 + 2 * 16 + l15) * 128 + (ko ^ swz));
      bfrag8 a3 = *(const bfrag8*)(smC + (wm * 64 + 3 * 16 + l15) * 128 + (ko ^ swz));
      bfrag8 g0 = *(const bfrag8*)(smC + 16384 + (wn * 64 + 0 * 16 + l15) * 128 + (ko ^ swz));
      bfrag8 g1 = *(const bfrag8*)(smC + 16384 + (wn * 64 + 1 * 16 + l15) * 128 + (ko ^ swz));
      bfrag8 g2 = *(const bfrag8*)(smC + 16384 + (wn * 64 + 2 * 16 + l15) * 128 + (ko ^ swz));
      bfrag8 g3 = *(const bfrag8*)(smC + 16384 + (wn * 64 + 3 * 16 + l15) * 128 + (ko ^ swz));
      accg[0][0] = MFMA16(a0, g0, accg[0][0]); accg[0][1] = MFMA16(a0, g1, accg[0][1]);
      accg[0][2] = MFMA16(a0, g2, accg[0][2]); accg[0][3] = MFMA16(a0, g3, accg[0][3]);
      accg[1][0] = MFMA16(a1, g0, accg[1][0]); accg[1][1] = MFMA16(a1, g1, accg[1][1]);
      accg[1][2] = MFMA16(a1, g2, accg[1][2]); accg[1][3] = MFMA16(a1, g3, accg[1][3]);
      accg[2][0] = MFMA16(a2, g0, accg[2][0]); accg[2][1] = MFMA16(a2, g1, accg[2][1]);
      accg[2][2] = MFMA16(a2, g2, accg[2][2]); accg[2][3] = MFMA16(a2, g3, accg[2][3]);
      accg[3][0] = MFMA16(a3, g0, accg[3][0]); accg[3][1] = MFMA16(a3, g1, accg[3][1]);
      accg[3][2] = MFMA16(a3, g2, accg[3][2]); accg[3][3] = MFMA16(a3, g3, accg[3][3]);
      bfrag8 u0 = *(const bfrag8*)(smC + 32768 + (wn * 64 + 0 * 16 + l15) * 128 + (ko ^ swz));
      bfrag8 u1 = *(const bfrag8*)(smC + 32768 + (wn * 64 + 1 * 16 + l15) * 128 + (ko ^ swz));
      bfrag8 u2 = *(const bfrag8*)(smC + 32768 + (wn * 64 + 2 * 16 + l15) * 128 + (ko ^ swz));
      bfrag8 u3 = *(const bfrag8*)(smC + 32768 + (wn * 64 + 3 * 16 + l15) * 128 + (ko ^ swz));
      accu[0][0] = MFMA16(a0, u0, accu[0][0]); accu[0][1] = MFMA16(a0, u1, accu[0][1]);
      accu[0][2] = MFMA16(a0, u2, accu[0][2]); accu[0][3] = MFMA16(a0, u3, accu[0][3]);
      accu[1][0] = MFMA16(a1, u0, accu[1][0]); accu[1][1] = MFMA16(a1, u1, accu[1][1]);
      accu[1][2] = MFMA16(a1, u2, accu[1][2]); accu[1][3] = MFMA16(a1, u3, accu[1][3]);
      accu[2][0] = MFMA16(a2, u0, accu[2][0]); accu[2][1] = MFMA16(a2, u1, accu[2][1]);
      accu[2][2] = MFMA16(a2, u2, accu[2][2]); accu[2][3] = MFMA16(a2, u3, accu[2][3]);
      accu[3][0] = MFMA16(a3, u0, accu[3][0]); accu[3][1] = MFMA16(a3, u1, accu[3][1]);
      accu[3][2] = MFMA16(a3, u2, accu[3][2]); accu[3][3] = MFMA16(a3, u3, accu[3][3]);
    }
  }

#pragma unroll
  for (int i = 0; i < 4; ++i) {
#pragma unroll
    for (int j2 = 0; j2 < 4; ++j2) {
      const int mr = m0 + wm * 64 + i * 16 + lhi * 4;
      const int nc = n0 + wn * 64 + j2 * 16 + l15;
#pragma unroll
      for (int r = 0; r < 4; ++r) {
        const float g = accg[i][j2][r];
        const float u = accu[i][j2][r];
        const float s = g / (1.f + __expf(-g));
        outB[(size_t)(mr + r) * N + nc] = bf_bits(u * s);
      }
    }
  }
}

// ---------------- causal flash attention (8 waves, QBLK=128, KVBLK=64) ----------------
__global__ __launch_bounds__(512) void k_attn(const u16* __restrict__ qkv,
                                              const u16* __restrict__ vtg,
                                              u16* __restrict__ out) {
  const int S = 2048, LD = 6144;
  const float scale = 0.0883883476483184405f;  // 1/sqrt(128)
  const int fid = blockIdx.x;       // 0..511
  const int p = fid >> 1, s = fid & 1;
  const int bh = p & 31;
  const int pq = p >> 5;            // 0..7
  const int qt = s ? (15 - pq) : pq;
  const int b = bh >> 4, hh = bh & 15;
  const int t = threadIdx.x;
  const int wave = t >> 6, lane = t & 63;
  const int l15 = lane & 15, lhi = lane >> 4;
  const int lhi16 = lhi * 16;
  const int swz = (l15 & 7) << 4;

  __shared__ u16 Kt[64 * 128];
  __shared__ u16 Vt[128 * 64];
  __shared__ u16 Pl[8][16][72];
  char* KtC = (char*)Kt;
  char* VtC = (char*)Vt;

  const int qrow = qt * 128 + wave * 16 + l15;
  const size_t qoff = (size_t)(b * S + qrow) * LD + hh * 128 + lhi * 8;
  bfrag8 qf[4];
#pragma unroll
  for (int ks = 0; ks < 4; ++ks) qf[ks] = *(const bfrag8*)(qkv + qoff + ks * 32);

  f32x4 oacc[8];
#pragma unroll
  for (int j = 0; j < 8; ++j) oacc[j] = (f32x4){0.f, 0.f, 0.f, 0.f};
  float m_i[4], l_i[4];
#pragma unroll
  for (int r = 0; r < 4; ++r) { m_i[r] = -INFINITY; l_i[r] = 0.f; }

  const int q_my = qt * 128 + wave * 16 + lhi * 4;
  const int q_wave_last = qt * 128 + wave * 16 + 15;

  const int keyA = t >> 4, keyB = 32 + (t >> 4);
  const int oK = (t & 15) * 16;
  const int dA = t >> 3, dB = 64 + (t >> 3);
  const int oV = (t & 7) * 16;
  const u16* kbase = qkv + (size_t)(b * S) * LD + 2048 + hh * 128;
  const u16* vbase = vtg + (size_t)bh * 128 * S;
  const u16* ksrcA = kbase + (size_t)keyA * LD + ((oK ^ ((keyA & 7) << 4)) >> 1);
  const u16* ksrcB = kbase + (size_t)keyB * LD + ((oK ^ ((keyB & 7) << 4)) >> 1);
  const u16* vsrcA = vbase + (size_t)dA * S + ((oV ^ ((dA & 7) << 4)) >> 1);
  const u16* vsrcB = vbase + (size_t)dB * S + ((oV ^ ((dB & 7) << 4)) >> 1);
  const unsigned int ldso0 = wave * 1024 + lane * 16;
  const unsigned int ldso1 = 8192 + wave * 1024 + lane * 16;
  const size_t kstep = (size_t)64 * LD;

  const int kt_max = 2 * qt + 1;
  for (int kt = 0; kt <= kt_max; ++kt) {
    __syncthreads();
    gload16(ksrcA + (size_t)kt * kstep, KtC + ldso0);
    gload16(ksrcB + (size_t)kt * kstep, KtC + ldso1);
    gload16(vsrcA + kt * 64, VtC + ldso0);
    gload16(vsrcB + kt * 64, VtC + ldso1);
    __syncthreads();

    if (kt * 64 <= q_wave_last) {
      f32x4 sfr[4];
#pragma unroll
      for (int j = 0; j < 4; ++j) {
        sfr[j] = (f32x4){0.f, 0.f, 0.f, 0.f};
        const int krow = j * 16 + l15;
#pragma unroll
        for (int ks = 0; ks < 4; ++ks) {
          bfrag8 kf = *(const bfrag8*)(KtC + krow * 256 + ((ks * 64 + lhi16) ^ swz));
          sfr[j] = MFMA16(qf[ks], kf, sfr[j]);
        }
      }
      float sv[4][4], rmax[4];
#pragma unroll
      for (int r = 0; r < 4; ++r) rmax[r] = -INFINITY;
#pragma unroll
      for (int j = 0; j < 4; ++j) {
        const int key = kt * 64 + j * 16 + l15;
#pragma unroll
        for (int r = 0; r < 4; ++r) {
          float v = sfr[j][r] * scale;
          v = (key <= q_my + r) ? v : -INFINITY;
          sv[j][r] = v;
          rmax[r] = fmaxf(rmax[r], v);
        }
      }
#pragma unroll
      for (int r = 0; r < 4; ++r) {
        float v = rmax[r];
        v = fmaxf(v, __shfl_xor(v, 1));
        v = fmaxf(v, __shfl_xor(v, 2));
        v = fmaxf(v, __shfl_xor(v, 4));
        v = fmaxf(v, __shfl_xor(v, 8));
        rmax[r] = v;
      }
      float alpha[4], rsum[4];
#pragma unroll
      for (int r = 0; r < 4; ++r) {
        float mn = fmaxf(m_i[r], rmax[r]);
        alpha[r] = __expf(m_i[r] - mn);
        m_i[r] = mn;
        rsum[r] = 0.f;
      }
#pragma unroll
      for (int j = 0; j < 4; ++j) {
#pragma unroll
        for (int r = 0; r < 4; ++r) {
          float p2 = __expf(sv[j][r] - m_i[r]);
          rsum[r] += p2;
          Pl[wave][lhi * 4 + r][j * 16 + l15] = bf_bits(p2);
        }
      }
#pragma unroll
      for (int r = 0; r < 4; ++r) {
        float v = rsum[r];
        v += __shfl_xor(v, 1); v += __shfl_xor(v, 2);
        v += __shfl_xor(v, 4); v += __shfl_xor(v, 8);
        l_i[r] = l_i[r] * alpha[r] + v;
      }
#pragma unroll
      for (int j = 0; j < 8; ++j)
#pragma unroll
        for (int r = 0; r < 4; ++r) oacc[j][r] *= alpha[r];

#pragma unroll
      for (int ks2 = 0; ks2 < 2; ++ks2) {
        bfrag8 pf = *(const bfrag8*)&Pl[wave][l15][ks2 * 32 + lhi * 8];
#pragma unroll
        for (int j = 0; j < 8; ++j) {
          const int d = j * 16 + l15;
          bfrag8 vf = *(const bfrag8*)(VtC + d * 128 + ((ks2 * 64 + lhi16) ^ swz));
          oacc[j] = MFMA16(pf, vf, oacc[j]);
        }
      }
    }
  }

#pragma unroll
  for (int r = 0; r < 4; ++r) {
    const float inv = 1.f / l_i[r];
    const size_t tok = (size_t)b * S + qt * 128 + wave * 16 + lhi * 4 + r;
#pragma unroll
    for (int j = 0; j < 8; ++j)
      out[tok * 2048 + hh * 128 + j * 16 + l15] = bf_bits(oacc[j][r] * inv);
  }
}

// ---------------- launch ----------------
extern "C" void kernel_launch(void* const* d_in, const int* in_sizes, int n_in,
                              void* d_out, int out_size, void* d_ws, size_t ws_size,
                              hipStream_t stream) {
  (void)in_sizes; (void)n_in; (void)out_size; (void)ws_size;
  const float* x      = (const float*)d_in[0];
  const float* w_qkv  = (const float*)d_in[1];
  const float* w_o    = (const float*)d_in[2];
  const float* w_up   = (const float*)d_in[3];
  const float* w_gate = (const float*)d_in[4];
  const float* w_down = (const float*)d_in[5];
  const float* scale1 = (const float*)d_in[6];
  const float* scale2 = (const float*)d_in[7];
  float* out = (float*)d_out;

  u16* B       = (u16*)d_ws;
  u16* wqkvT   = B;                               // [6144][2048]
  u16* woT     = wqkvT  + (size_t)6144 * 2048;    // [2048][2048]
  u16* wgateT  = woT    + (size_t)2048 * 2048;    // [8192][2048]
  u16* wupT    = wgateT + (size_t)8192 * 2048;    // [8192][2048]
  u16* wdownT  = wupT   + (size_t)8192 * 2048;    // [2048][8192]
  u16* xn      = wdownT + (size_t)2048 * 8192;    // [4096][2048]
  u16* qkvb    = xn     + (size_t)4096 * 2048;    // [4096][6144]
  u16* attnb   = qkvb   + (size_t)4096 * 6144;    // [4096][2048]
  float* y1    = (float*)(attnb + (size_t)4096 * 2048);  // [4096][2048] f32
  u16* vtg     = (u16*)y1;      // alias: vtg dead before y1 written
  u16* hbuf    = qkvb;          // alias: qkv+attn dead after out-proj
  float* part0 = (float*)wqkvT;   // wqkvT+woT = exactly 4096*2048 f32, dead after out-proj
  float* part1 = (float*)wgateT;  // wgateT = exactly 4096*2048 f32, dead after mlp

  dim3 blk(256);
  k_transpose_bf16<<<dim3(192, 64), blk, 0, stream>>>(w_qkv,  wqkvT,  2048, 6144);
  k_transpose_bf16<<<dim3(64, 64),  blk, 0, stream>>>(w_o,    woT,    2048, 2048);
  k_transpose_bf16<<<dim3(256, 64), blk, 0, stream>>>(w_gate, wgateT, 2048, 8192);
  k_transpose_bf16<<<dim3(256, 64), blk, 0, stream>>>(w_up,   wupT,   2048, 8192);
  k_transpose_bf16<<<dim3(64, 256), blk, 0, stream>>>(w_down, wdownT, 8192, 2048);

  k_rmsnorm<<<4096, blk, 0, stream>>>(x, scale1, xn);
  k_gemm2<0, 2048, 0><<<dim3(24, 32), blk, 0, stream>>>(xn, wqkvT, 6144, nullptr, qkvb, nullptr);
  k_transpose_v<<<dim3(64, 4, 32), blk, 0, stream>>>(qkvb, vtg);
  k_attn<<<dim3(512), dim3(512), 0, stream>>>(qkvb, vtg, attnb);
  k_gemm<1, 2048, 1><<<dim3(16, 32), blk, 0, stream>>>(attnb, woT, 4096, 2048, y1, nullptr, x, nullptr);
  k_rmsnorm<<<4096, blk, 0, stream>>>(y1, scale2, xn);
  k_gemm_mlp<2048><<<dim3(64, 32), blk, 0, stream>>>(xn, wgateT, wupT, 8192, hbuf);
  // down: split-K x3 dual-n (768 blocks = 3/CU). z partials -> part0/part1/out.
  k_gemm2s<8192><<<dim3(8, 32, 3), blk, 0, stream>>>(hbuf, wdownT, 2048, part0, part1, out);
  k_combine3<<<8192, blk, 0, stream>>>(out, part0, part1, y1);
}